// Round 10
// baseline (12701.311 us; speedup 1.0000x reference)
//
#include <hip/hip_runtime.h>
#include <math.h>

#define B_   8
#define L_   2048
#define E_   768
#define H_   512
#define G4_  2048   // 4*H
#define CL_  512    // L chunk length

static __device__ __forceinline__ float sigm(float x){ return 1.0f/(1.0f+expf(-x)); }
static __device__ __forceinline__ float ftanh(float x){
  float ax = fabsf(x);
  float e  = expf(2.0f*ax);            // inf for large ax -> r = 1
  float r  = 1.0f - 2.0f/(e+1.0f);
  return copysignf(r, x);
}

// ---------------------------------------------------------------------------
// C[M,N] = A'[m,:K] . W[n,:K]^T + bias1[n] (+bias2[n])
// 128x128 tile, BK=16, 256 threads, 8x8 micro tile.
// ---------------------------------------------------------------------------
__global__ __launch_bounds__(256) void gemm128(
    const float* __restrict__ A, const float* __restrict__ W,
    const float* __restrict__ bias1, const float* __restrict__ bias2,
    float* __restrict__ C, int M, int N, int K, int CL, int Ltot, int c0)
{
  __shared__ float As[16][132];
  __shared__ float Bs[16][132];
  const int tid = threadIdx.x;
  const int bm = blockIdx.y * 128, bn = blockIdx.x * 128;

  const int r  = tid >> 1;          // 0..127 (loader row)
  const int kq = (tid & 1) * 8;     // 0 or 8 (loader k-offset)
  const int am = bm + r;
  const int ab = am / CL, al = am % CL;
  const float* Arow = A + ((size_t)ab * Ltot + c0 + al) * K;
  const float* Wrow = W + (size_t)(bn + r) * K;

  const int tx = tid & 15, ty = tid >> 4;
  float acc[8][8] = {};

  for (int k0 = 0; k0 < K; k0 += 16) {
    float4 a0 = *(const float4*)(Arow + k0 + kq);
    float4 a1 = *(const float4*)(Arow + k0 + kq + 4);
    float4 w0 = *(const float4*)(Wrow + k0 + kq);
    float4 w1 = *(const float4*)(Wrow + k0 + kq + 4);
    __syncthreads();
    As[kq+0][r]=a0.x; As[kq+1][r]=a0.y; As[kq+2][r]=a0.z; As[kq+3][r]=a0.w;
    As[kq+4][r]=a1.x; As[kq+5][r]=a1.y; As[kq+6][r]=a1.z; As[kq+7][r]=a1.w;
    Bs[kq+0][r]=w0.x; Bs[kq+1][r]=w0.y; Bs[kq+2][r]=w0.z; Bs[kq+3][r]=w0.w;
    Bs[kq+4][r]=w1.x; Bs[kq+5][r]=w1.y; Bs[kq+6][r]=w1.z; Bs[kq+7][r]=w1.w;
    __syncthreads();
    #pragma unroll
    for (int k = 0; k < 16; ++k) {
      float4 x0 = *(const float4*)&As[k][ty*4];
      float4 x1 = *(const float4*)&As[k][64 + ty*4];
      float4 y0 = *(const float4*)&Bs[k][tx*4];
      float4 y1 = *(const float4*)&Bs[k][64 + tx*4];
      float av[8] = {x0.x,x0.y,x0.z,x0.w, x1.x,x1.y,x1.z,x1.w};
      float bv[8] = {y0.x,y0.y,y0.z,y0.w, y1.x,y1.y,y1.z,y1.w};
      #pragma unroll
      for (int i=0;i<8;++i)
        #pragma unroll
        for (int j=0;j<8;++j)
          acc[i][j] += av[i]*bv[j];
    }
  }

  float bs[8];
  #pragma unroll
  for (int j=0;j<4;++j) {
    int c0n = bn + tx*4 + j, c1n = bn + 64 + tx*4 + j;
    bs[j]   = bias1[c0n] + (bias2 ? bias2[c0n] : 0.0f);
    bs[4+j] = bias1[c1n] + (bias2 ? bias2[c1n] : 0.0f);
  }
  #pragma unroll
  for (int i=0;i<8;++i) {
    int row = bm + ((i<4) ? (ty*4+i) : (64 + ty*4 + (i-4)));
    float4 o0 = { acc[i][0]+bs[0], acc[i][1]+bs[1], acc[i][2]+bs[2], acc[i][3]+bs[3] };
    float4 o1 = { acc[i][4]+bs[4], acc[i][5]+bs[5], acc[i][6]+bs[6], acc[i][7]+bs[7] };
    *(float4*)&C[(size_t)row*N + bn + tx*4]      = o0;
    *(float4*)&C[(size_t)row*N + bn + 64 + tx*4] = o1;
  }
}

// ---------------------------------------------------------------------------
// Persistent recurrence v10: XCD-claimed placement => exchange through the
// block's OWN XCD L2 (deterministic, not heuristic).
// 256 blocks x 256 threads, 136 KB LDS -> exactly 1 block/CU -> all 256 CUs
// filled -> exactly 32 blocks per XCD. Each block reads its physical XCD id
// (s_getreg HW_REG_XCC_ID, HW-verified m09) and claims
// (batch = xcc, m = atomicAdd(cnt[xcc])): all 32 blocks of batch b are ON
// XCD b by construction. h exchange: tagged u64 (tag=t+1 | h bits),
// sc0 store (-> shared local L2) + agent store (MALL net);
// poll = paired sc0 loads (bypass L1, served by local L2, ~250cy RT) with
// every-16th-probe agent escalation (progress even if cache model is wrong
// in either direction; tags self-validate; worst case slow, never wrong).
// LDS-resident weights (r6 layout, 0 conflicts), parity double-buffered h
// staging, self-bypass of own words, ONE __syncthreads per step.
// ---------------------------------------------------------------------------
__global__ __launch_bounds__(256, 1) void recur10(
    const float* __restrict__ Xp,    // [B][CL][G4] gate preactivations
    const float* __restrict__ Whh,   // [G4][H]
    float* __restrict__ enc_out,     // [B][L][H]
    unsigned long long* __restrict__ hb2,  // [2][B][H] tagged words
    float* __restrict__ cbuf,        // [B][H]
    float* __restrict__ hT,          // [B][H] final h (plain)
    int* __restrict__ cnt,           // [8] per-XCD claim counters (zeroed)
    int t0, int nsteps)
{
  const int tid = threadIdx.x;

  __shared__ int   s_bm;
  __shared__ float4 wlds[4*16*8*16]; // [gi][c][k][q] float4 = 128 KB
  __shared__ float  hsh[2][512];     // 4 KB (parity-double-buffered h)
  __shared__ float  xpsh[2][64];     // 512 B

  // ---- claim (batch, m) on THIS block's physical XCD ----
  if (tid == 0) {
    unsigned xcc;
    asm volatile("s_getreg_b32 %0, hwreg(HW_REG_XCC_ID)" : "=s"(xcc));
    xcc &= 7u;
    int slot = atomicAdd(cnt + xcc, 1) & 31;
    s_bm = (int)((xcc << 5) | (unsigned)slot);
  }
  __syncthreads();
  const int b = s_bm >> 5;           // batch == this XCD's id
  const int m = s_bm & 31;           // h-slice 0..31
  const int c = tid >> 4;            // cluster 0..15
  const int q = tid & 15;            // lane within cluster
  const int j = m*16 + c;            // owned h index

  // stage weights once: wlds[gi*2048 + c*128 + k*16 + q] = Whh[gi*512+j][4q+64k..+3]
  {
    #pragma unroll
    for (int gi = 0; gi < 4; ++gi) {
      const float4* wrow = (const float4*)(Whh + ((size_t)(gi*H_ + j))*H_) + q;
      #pragma unroll
      for (int k = 0; k < 8; ++k)
        wlds[gi*2048 + c*128 + k*16 + q] = wrow[k*16];
    }
  }

  float cc = 0.0f;
  if (q == 0) cc = cbuf[b*H_ + j];

  // Xp slice prefetch (one step ahead): tid<64 -> gi=tid>>4, jj=tid&15
  float xv = 0.0f;
  if (tid < 64)
    xv = Xp[((size_t)(b*CL_ + 0))*G4_ + (size_t)(tid>>4)*H_ + m*16 + (tid&15)];

  const bool own = ((tid >> 3) == m);  // this thread's 2 words are block-own
  __syncthreads();                     // weights staged, claim visible

  for (int s = 0; s < nsteps; ++s) {
    const int t = t0 + s;
    const unsigned ut = (unsigned)t;
    const int p = s & 1;

    // stage prefetched Xp; issue next step's prefetch (hidden under poll)
    if (tid < 64) {
      xpsh[p][tid] = xv;
      if (s + 1 < nsteps)
        xv = Xp[((size_t)(b*CL_ + s + 1))*G4_ + (size_t)(tid>>4)*H_ + m*16 + (tid&15)];
    }

    // poll 2 tagged h-words until tag == t (self-bypass own words, s>0)
    if (!(own && s > 0)) {
      const size_t base = ((size_t)(t & 1))*(B_*H_) + (size_t)b*H_ + tid*2;
      const unsigned long long ad = (unsigned long long)(hb2 + base);
      unsigned long long v0 = 0, v1 = 0;
      bool d0 = false, d1 = false;
      int it = 0;
      for (;;) {
        unsigned long long x0, x1;
        // paired probe: 2 loads, 1 round trip; sc0 = bypass L1, hit local L2
        asm volatile("global_load_dwordx2 %0, %2, off sc0\n\t"
                     "global_load_dwordx2 %1, %2, off offset:8 sc0\n\t"
                     "s_waitcnt vmcnt(0)"
                     : "=&v"(x0), "=&v"(x1) : "v"(ad) : "memory");
        if (!d0) { v0 = x0; d0 = ((unsigned)(v0 >> 32) == ut); }
        if (!d1) { v1 = x1; d1 = ((unsigned)(v1 >> 32) == ut); }
        if (d0 && d1) break;
        if ((++it & 15) == 0) {        // rare escalation: coherent agent path
          if (!d0) {
            unsigned long long a0 = __hip_atomic_load(hb2 + base, __ATOMIC_RELAXED, __HIP_MEMORY_SCOPE_AGENT);
            if ((unsigned)(a0 >> 32) == ut) { v0 = a0; d0 = true; }
          }
          if (!d1) {
            unsigned long long a1 = __hip_atomic_load(hb2 + base + 1, __ATOMIC_RELAXED, __HIP_MEMORY_SCOPE_AGENT);
            if ((unsigned)(a1 >> 32) == ut) { v1 = a1; d1 = true; }
          }
          if (d0 && d1) break;
        }
      }
      union { unsigned u; float f; } a0, a1;
      a0.u = (unsigned)v0; a1.u = (unsigned)v1;
      hsh[p][2*tid]   = a0.f;
      hsh[p][2*tid+1] = a1.f;
    }
    __syncthreads();                               // the ONLY per-step barrier

    // act-lane xpsh reads issued early (hidden under FMA)
    float xg0=0.f, xg1=0.f, xg2=0.f, xg3=0.f;
    if (q == 0) {
      xg0 = xpsh[p][c];      xg1 = xpsh[p][16+c];
      xg2 = xpsh[p][32+c];   xg3 = xpsh[p][48+c];
    }

    // 4 gates x 32 cols per thread: weights + h from LDS (conflict-free)
    float a0=0.f, a1=0.f, a2=0.f, a3=0.f;
    const int wb = c*128 + q;
    #pragma unroll
    for (int k = 0; k < 8; ++k) {
      float4 h4 = *(const float4*)&hsh[p][q*4 + k*64];
      float4 w0 = wlds[0*2048 + wb + k*16];
      float4 w1 = wlds[1*2048 + wb + k*16];
      float4 w2 = wlds[2*2048 + wb + k*16];
      float4 w3 = wlds[3*2048 + wb + k*16];
      a0 = fmaf(w0.x,h4.x, fmaf(w0.y,h4.y, fmaf(w0.z,h4.z, fmaf(w0.w,h4.w, a0))));
      a1 = fmaf(w1.x,h4.x, fmaf(w1.y,h4.y, fmaf(w1.z,h4.z, fmaf(w1.w,h4.w, a1))));
      a2 = fmaf(w2.x,h4.x, fmaf(w2.y,h4.y, fmaf(w2.z,h4.z, fmaf(w2.w,h4.w, a2))));
      a3 = fmaf(w3.x,h4.x, fmaf(w3.y,h4.y, fmaf(w3.z,h4.z, fmaf(w3.w,h4.w, a3))));
    }
    // reduce across the 16-lane cluster
    #pragma unroll
    for (int msk = 1; msk < 16; msk <<= 1) {
      a0 += __shfl_xor(a0, msk, 64);
      a1 += __shfl_xor(a1, msk, 64);
      a2 += __shfl_xor(a2, msk, 64);
      a3 += __shfl_xor(a3, msk, 64);
    }

    // activation in-register on lane q==0; publish tagged word FIRST
    if (q == 0) {
      float g0 = a0 + xg0, g1 = a1 + xg1, g2 = a2 + xg2, g3 = a3 + xg3;
      cc = sigm(g1)*cc + sigm(g0)*ftanh(g2);
      float hn = sigm(g3)*ftanh(cc);
      union { float f; unsigned u; } hu; hu.f = hn;
      unsigned long long wv =
          (((unsigned long long)(ut + 1u)) << 32) | (unsigned long long)hu.u;
      const size_t idxN = ((size_t)((t+1) & 1))*(B_*H_) + (size_t)b*H_ + j;
      // fast publish into this XCD's L2 (consumers are same-XCD by claim)
      asm volatile("global_store_dwordx2 %0, %1, off sc0"
                   :: "v"((unsigned long long)(hb2 + idxN)), "v"(wv) : "memory");
      // safety-net publish (coherent at agent scope; same value)
      __hip_atomic_store(hb2 + idxN, wv,
                         __ATOMIC_RELAXED, __HIP_MEMORY_SCOPE_AGENT);
      hsh[p^1][j] = hn;                  // self-bypass for next step
      enc_out[((size_t)b*L_ + t)*H_ + j] = hn;
      if (t == L_ - 1) hT[b*H_ + j] = hn;
    }
  }
  if (q == 0) cbuf[b*H_ + j] = cc;
}

// ---------------------------------------------------------------------------
// out[b][n] = act( x1[b].W1[n,:K1] + (x2? x2[b].W2[n,:K2]) + bias1[n] (+bias2) )
// ---------------------------------------------------------------------------
__global__ __launch_bounds__(256) void dual_mv(
    const float* __restrict__ x1, const float* __restrict__ W1, int ld1, int K1,
    const float* __restrict__ x2, const float* __restrict__ W2, int ld2, int K2,
    const float* __restrict__ bias1, const float* __restrict__ bias2,
    float* __restrict__ out, int N, int act)
{
  const int w = blockIdx.x*4 + (threadIdx.x>>6);
  const int lane = threadIdx.x & 63;
  const int b = w / N, n = w % N;
  float s = 0.0f;
  for (int k = lane*4; k < K1; k += 256) {
    float4 xv = *(const float4*)(x1 + (size_t)b*K1 + k);
    float4 wv = *(const float4*)(W1 + (size_t)n*ld1 + k);
    s += xv.x*wv.x + xv.y*wv.y + xv.z*wv.z + xv.w*wv.w;
  }
  if (x2) {
    for (int k = lane*4; k < K2; k += 256) {
      float4 xv = *(const float4*)(x2 + (size_t)b*K2 + k);
      float4 wv = *(const float4*)(W2 + (size_t)n*ld2 + k);
      s += xv.x*wv.x + xv.y*wv.y + xv.z*wv.z + xv.w*wv.w;
    }
  }
  #pragma unroll
  for (int m=32; m>0; m>>=1) s += __shfl_xor(s, m, 64);
  if (lane == 0) {
    float r = s + bias1[n] + (bias2 ? bias2[n] : 0.0f);
    if (act) r = tanhf(r);
    out[(size_t)b*N + n] = r;
  }
}

__global__ void dec_cell(const float* __restrict__ g, float* __restrict__ c,
                         float* __restrict__ ht)
{
  int i = blockIdx.x*256 + threadIdx.x;     // 4096 threads
  int b = i >> 9, j = i & 511;
  const float* gb = g + (size_t)b*G4_;
  float gi_ = gb[j], gf = gb[H_+j], gg = gb[2*H_+j], go = gb[3*H_+j];
  float cc = c[i];
  cc = sigm(gf)*cc + sigm(gi_)*tanhf(gg);
  ht[i] = sigm(go)*tanhf(cc);
  c[i]  = cc;
}

__global__ __launch_bounds__(256) void dec_att(
    const float* __restrict__ inp, const float* __restrict__ ctx,
    const float* __restrict__ V, float* __restrict__ att)
{
  const int w = blockIdx.x*4 + (threadIdx.x>>6);  // w = b*L_ + l
  const int lane = threadIdx.x & 63;
  const int b = w >> 11;
  const float* cr = ctx + (size_t)w*H_;
  const float* ip = inp + (size_t)b*H_;
  float s = 0.0f;
  #pragma unroll
  for (int i=0;i<2;++i) {
    int k = lane*4 + i*256;
    float4 c4 = *(const float4*)(cr+k);
    float4 i4 = *(const float4*)(ip+k);
    float4 v4 = *(const float4*)(V+k);
    s += v4.x*tanhf(i4.x+c4.x) + v4.y*tanhf(i4.y+c4.y)
       + v4.z*tanhf(i4.z+c4.z) + v4.w*tanhf(i4.w+c4.w);
  }
  #pragma unroll
  for (int m=32; m>0; m>>=1) s += __shfl_xor(s, m, 64);
  if (lane == 0) att[w] = s;
}

__global__ __launch_bounds__(256) void dec_softmax(
    const float* __restrict__ att, const float* __restrict__ enc,
    int iter, int* __restrict__ chosen,
    float* __restrict__ out_alpha, float* __restrict__ out_ptr,
    float* __restrict__ x_next)
{
  const int b = blockIdx.x, tid = threadIdx.x;
  __shared__ float rv[256]; __shared__ int ri[256];
  __shared__ float s_mx, s_sum; __shared__ int s_idx;
  const int banned = iter ? chosen[b] : -1;
  float a[8]; float mx = -INFINITY;
  #pragma unroll
  for (int i=0;i<8;++i) {
    int l = (i<<8)+tid;
    float v = att[(size_t)b*L_ + l];
    if (l == banned) v = -INFINITY;
    a[i] = v; mx = fmaxf(mx, v);
  }
  rv[tid]=mx; __syncthreads();
  for (int s=128;s>0;s>>=1){ if (tid<s) rv[tid]=fmaxf(rv[tid],rv[tid+s]); __syncthreads(); }
  if (tid==0) s_mx = rv[0];
  __syncthreads();
  const float MX = s_mx;
  __syncthreads();
  float sum = 0.0f;
  #pragma unroll
  for (int i=0;i<8;++i) {
    int l = (i<<8)+tid;
    float pexp = (l == banned) ? 0.0f : expf(a[i]-MX);
    sum += pexp; a[i] = pexp;
  }
  rv[tid]=sum; __syncthreads();
  for (int s=128;s>0;s>>=1){ if (tid<s) rv[tid]+=rv[tid+s]; __syncthreads(); }
  if (tid==0) s_sum = rv[0];
  __syncthreads();
  const float inv = 1.0f/s_sum;
  __syncthreads();
  // argmax (first-occurrence on ties, matches jnp.argmax)
  float vb = -1.0f; int ib = 1<<30;
  #pragma unroll
  for (int i=0;i<8;++i) {
    int l = (i<<8)+tid;
    if (l != banned) { float v = a[i]; if (v > vb || (v == vb && l < ib)) { vb=v; ib=l; } }
  }
  rv[tid]=vb; ri[tid]=ib; __syncthreads();
  for (int s=128;s>0;s>>=1) {
    if (tid<s) {
      float v2=rv[tid+s]; int i2=ri[tid+s];
      if (v2 > rv[tid] || (v2 == rv[tid] && i2 < ri[tid])) { rv[tid]=v2; ri[tid]=i2; }
    }
    __syncthreads();
  }
  if (tid==0) {
    s_idx = ri[0];
    out_ptr[b*2+iter] = (float)ri[0];
    if (iter==0) chosen[b] = ri[0];
  }
  __syncthreads();
  #pragma unroll
  for (int i=0;i<8;++i) {
    int l = (i<<8)+tid;
    out_alpha[((size_t)b*2+iter)*L_ + l] = a[i]*inv;
  }
  const int idx = s_idx;
  for (int j=tid; j<H_; j+=256)
    x_next[(size_t)b*H_ + j] = enc[((size_t)b*L_ + idx)*H_ + j];
}

__global__ void dec_hidden1(const float* __restrict__ ctx, const float* __restrict__ alpha_all,
                            int iter, float* __restrict__ part)
{
  const int b = blockIdx.x >> 4, ch = blockIdx.x & 15;
  const int j = threadIdx.x;  // 512
  const float* al = alpha_all + ((size_t)b*2+iter)*L_ + ch*128;
  const float* cp = ctx + ((size_t)b*L_ + ch*128)*H_ + j;
  float s = 0.0f;
  for (int l=0; l<128; ++l) s += cp[(size_t)l*H_] * al[l];
  part[((size_t)b*16+ch)*H_ + j] = s;
}

__global__ void dec_hidden2(const float* __restrict__ part, float* __restrict__ hid)
{
  int i = blockIdx.x*256 + threadIdx.x;  // 4096
  int b = i >> 9, j = i & 511;
  float s = 0.0f;
  #pragma unroll
  for (int ch=0; ch<16; ++ch) s += part[((size_t)b*16+ch)*H_ + j];
  hid[i] = s;
}

// ---------------------------------------------------------------------------
extern "C" void kernel_launch(void* const* d_in, const int* in_sizes, int n_in,
                              void* d_out, int out_size, void* d_ws, size_t ws_size,
                              hipStream_t stream)
{
  const float* emb   = (const float*)d_in[0];
  const float* x0    = (const float*)d_in[1];
  const float* W_ih  = (const float*)d_in[2];
  const float* W_hh  = (const float*)d_in[3];
  const float* b_ih  = (const float*)d_in[4];
  const float* b_hh  = (const float*)d_in[5];
  const float* Wd_in = (const float*)d_in[6];
  const float* bd_in = (const float*)d_in[7];
  const float* Wd_hh = (const float*)d_in[8];
  const float* bd_hh = (const float*)d_in[9];
  const float* W_inp = (const float*)d_in[10];
  const float* b_inp = (const float*)d_in[11];
  const float* Wc    = (const float*)d_in[12];
  const float* bc    = (const float*)d_in[13];
  const float* V     = (const float*)d_in[14];
  const float* W_out = (const float*)d_in[15];
  const float* b_out = (const float*)d_in[16];

  float* ws  = (float*)d_ws;
  float* XP  = ws;                              // 8,388,608 floats (chunk Xproj)
  float* CTX = ws;                              // reused after recurrence
  float* ENC = XP + (size_t)8388608;            // 8,388,608 floats
  unsigned long long* HB2 = (unsigned long long*)(ENC + (size_t)8388608); // 8192 u64
  int*   CNT = (int*)(HB2 + 8192);              // 32 ints ([4 chunks][8 XCDs])
  float* HB  = (float*)(CNT + 32);              // 4096 (h_T)
  float* CB  = HB + 4096;                       // 4096 (c state)
  float* DG  = CB + 4096;                       // 16384
  float* HT  = DG + 16384;                      // 4096
  float* INP = HT + 4096;                       // 4096
  float* ATT = INP + 4096;                      // 16384
  float* HID = ATT + 16384;                     // 4096
  float* XN  = HID + 4096;                      // 4096
  float* HD  = XN + 4096;                       // 4096
  float* PART = HD + 4096;                      // 65536
  int* CHOSEN = (int*)(PART + 65536);           // 8

  // zero tagged h buffer (tag0 = h0=0), claim counters, h_T, c0 — contiguous
  hipMemsetAsync(HB2, 0,
      8192*sizeof(unsigned long long) + 32*sizeof(int) + (4096+4096)*sizeof(float),
      stream);

  // ---- encoder: chunked Xproj GEMM + XCD-local claimed recurrence ----
  for (int c=0; c<4; ++c) {
    gemm128<<<dim3(G4_/128, (B_*CL_)/128), 256, 0, stream>>>(
        emb, W_ih, b_ih, b_hh, XP, B_*CL_, G4_, E_, CL_, L_, c*CL_);
    recur10<<<256, 256, 0, stream>>>(XP, W_hh, ENC, HB2, CB, HB, CNT + c*8,
                                     c*CL_, CL_);
  }
  // ---- ctx = enc_out @ Wc^T + bc  (reuses XP region) ----
  gemm128<<<dim3(H_/128, (B_*L_)/128), 256, 0, stream>>>(
      ENC, Wc, bc, nullptr, CTX, B_*L_, H_, H_, L_, L_, 0);

  // ---- decoder: 2 pointer steps ----
  float* out = (float*)d_out;
  const float* x_cur = x0;
  const float* h_cur = HB;
  for (int iter=0; iter<2; ++iter) {
    dual_mv<<<(B_*G4_)/4, 256, 0, stream>>>(x_cur, Wd_in, H_, H_,
                                            h_cur, Wd_hh, H_, H_,
                                            bd_in, bd_hh, DG, G4_, 0);
    dec_cell<<<16, 256, 0, stream>>>(DG, CB, HT);
    dual_mv<<<(B_*H_)/4, 256, 0, stream>>>(HT, W_inp, H_, H_,
                                           nullptr, nullptr, 0, 0,
                                           b_inp, nullptr, INP, H_, 0);
    dec_att<<<(B_*L_)/4, 256, 0, stream>>>(INP, CTX, V, ATT);
    dec_softmax<<<B_, 256, 0, stream>>>(ATT, ENC, iter, CHOSEN, out, out + 32768, XN);
    dec_hidden1<<<B_*16, 512, 0, stream>>>(CTX, out, iter, PART);
    dec_hidden2<<<16, 256, 0, stream>>>(PART, HID);
    dual_mv<<<(B_*H_)/4, 256, 0, stream>>>(HID, W_out, 2*H_, H_,
                                           HT, W_out + H_, 2*H_, H_,
                                           b_out, nullptr, HD, H_, 1);
    x_cur = XN; h_cur = HD;
  }
}

// Round 11
// 9078.178 us; speedup vs baseline: 1.3991x; 1.3991x over previous
//
#include <hip/hip_runtime.h>
#include <math.h>

#define B_   8
#define L_   2048
#define E_   768
#define H_   512
#define G4_  2048   // 4*H
#define CL_  512    // L chunk length

static __device__ __forceinline__ float sigm(float x){ return 1.0f/(1.0f+expf(-x)); }
static __device__ __forceinline__ float ftanh(float x){
  float ax = fabsf(x);
  float e  = expf(2.0f*ax);            // inf for large ax -> r = 1
  float r  = 1.0f - 2.0f/(e+1.0f);
  return copysignf(r, x);
}

// ---------------------------------------------------------------------------
// C[M,N] = A'[m,:K] . W[n,:K]^T + bias1[n] (+bias2[n])
// 128x128 tile, BK=16, 256 threads, 8x8 micro tile.
// ---------------------------------------------------------------------------
__global__ __launch_bounds__(256) void gemm128(
    const float* __restrict__ A, const float* __restrict__ W,
    const float* __restrict__ bias1, const float* __restrict__ bias2,
    float* __restrict__ C, int M, int N, int K, int CL, int Ltot, int c0)
{
  __shared__ float As[16][132];
  __shared__ float Bs[16][132];
  const int tid = threadIdx.x;
  const int bm = blockIdx.y * 128, bn = blockIdx.x * 128;

  const int r  = tid >> 1;          // 0..127 (loader row)
  const int kq = (tid & 1) * 8;     // 0 or 8 (loader k-offset)
  const int am = bm + r;
  const int ab = am / CL, al = am % CL;
  const float* Arow = A + ((size_t)ab * Ltot + c0 + al) * K;
  const float* Wrow = W + (size_t)(bn + r) * K;

  const int tx = tid & 15, ty = tid >> 4;
  float acc[8][8] = {};

  for (int k0 = 0; k0 < K; k0 += 16) {
    float4 a0 = *(const float4*)(Arow + k0 + kq);
    float4 a1 = *(const float4*)(Arow + k0 + kq + 4);
    float4 w0 = *(const float4*)(Wrow + k0 + kq);
    float4 w1 = *(const float4*)(Wrow + k0 + kq + 4);
    __syncthreads();
    As[kq+0][r]=a0.x; As[kq+1][r]=a0.y; As[kq+2][r]=a0.z; As[kq+3][r]=a0.w;
    As[kq+4][r]=a1.x; As[kq+5][r]=a1.y; As[kq+6][r]=a1.z; As[kq+7][r]=a1.w;
    Bs[kq+0][r]=w0.x; Bs[kq+1][r]=w0.y; Bs[kq+2][r]=w0.z; Bs[kq+3][r]=w0.w;
    Bs[kq+4][r]=w1.x; Bs[kq+5][r]=w1.y; Bs[kq+6][r]=w1.z; Bs[kq+7][r]=w1.w;
    __syncthreads();
    #pragma unroll
    for (int k = 0; k < 16; ++k) {
      float4 x0 = *(const float4*)&As[k][ty*4];
      float4 x1 = *(const float4*)&As[k][64 + ty*4];
      float4 y0 = *(const float4*)&Bs[k][tx*4];
      float4 y1 = *(const float4*)&Bs[k][64 + tx*4];
      float av[8] = {x0.x,x0.y,x0.z,x0.w, x1.x,x1.y,x1.z,x1.w};
      float bv[8] = {y0.x,y0.y,y0.z,y0.w, y1.x,y1.y,y1.z,y1.w};
      #pragma unroll
      for (int i=0;i<8;++i)
        #pragma unroll
        for (int j=0;j<8;++j)
          acc[i][j] += av[i]*bv[j];
    }
  }

  float bs[8];
  #pragma unroll
  for (int j=0;j<4;++j) {
    int c0n = bn + tx*4 + j, c1n = bn + 64 + tx*4 + j;
    bs[j]   = bias1[c0n] + (bias2 ? bias2[c0n] : 0.0f);
    bs[4+j] = bias1[c1n] + (bias2 ? bias2[c1n] : 0.0f);
  }
  #pragma unroll
  for (int i=0;i<8;++i) {
    int row = bm + ((i<4) ? (ty*4+i) : (64 + ty*4 + (i-4)));
    float4 o0 = { acc[i][0]+bs[0], acc[i][1]+bs[1], acc[i][2]+bs[2], acc[i][3]+bs[3] };
    float4 o1 = { acc[i][4]+bs[4], acc[i][5]+bs[5], acc[i][6]+bs[6], acc[i][7]+bs[7] };
    *(float4*)&C[(size_t)row*N + bn + tx*4]      = o0;
    *(float4*)&C[(size_t)row*N + bn + 64 + tx*4] = o1;
  }
}

// ---------------------------------------------------------------------------
// Persistent recurrence v11: BARRIER-FREE dataflow. 256 blocks x 256 threads.
// Block (b = bid>>5, m = bid&31) owns batch b, h-indices [m*16, m*16+16)
// (XCD working set: 4 m-slices = 512 KB weights, L2-hot).
// No __syncthreads in the step loop: each WAVE stages the full 512-float h
// into its own private LDS region (lane l polls tagged words l+64k, k=0..7,
// coalesced; wave-uniform exit via __all). Write->read of that region is
// within one lockstep wave (compiler-ordered, + wave_barrier), so no block
// barrier is needed; waves advance independently, synchronized only by tags.
// Exchange protocol = r5 (best measured): tagged u64 (tag=t+1 | h bits),
// relaxed agent atomics, tag==t self-validating, parity double buffer.
// Induction: publish(t+1) requires all tag-t seen => every wave (all contain
// publishing clusters) completed its tag-(t-1) reads => overwrite safe.
// Weights stream from per-XCD L2 (r5 regime — overlaps the probe; LDS
// weights measured SLOWER serialized, r9). 16-lane cluster c owns all 4
// gates of h-index m*16+c; shfl_xor reduce; lane q==0 activates in
// registers, publishes, and keeps its 4 Xp values in registers (prefetched
// one step ahead; no LDS staging).
// ---------------------------------------------------------------------------
__global__ __launch_bounds__(256, 1) void recur11(
    const float* __restrict__ Xp,    // [B][CL][G4] gate preactivations
    const float* __restrict__ Whh,   // [G4][H]
    float* __restrict__ enc_out,     // [B][L][H]
    unsigned long long* __restrict__ hb2,  // [2][B][H] tagged words
    float* __restrict__ cbuf,        // [B][H]
    float* __restrict__ hT,          // [B][H] final h (plain)
    int t0, int nsteps)
{
  const int tid  = threadIdx.x;
  const int b    = blockIdx.x >> 5;  // batch 0..7
  const int m    = blockIdx.x & 31;  // h-slice 0..31
  const int wave = tid >> 6;
  const int lane = tid & 63;
  const int c    = tid >> 4;         // cluster 0..15
  const int q    = tid & 15;         // lane within cluster
  const int j    = m*16 + c;         // owned h index

  __shared__ float hws[4][512];      // per-wave h staging (8 KB total)

  float cc = 0.0f;
  float xv0=0.f, xv1=0.f, xv2=0.f, xv3=0.f;
  if (q == 0) {
    cc = cbuf[b*H_ + j];
    const float* xp0 = Xp + ((size_t)(b*CL_ + 0))*G4_ + j;
    xv0 = xp0[0]; xv1 = xp0[H_]; xv2 = xp0[2*H_]; xv3 = xp0[3*H_];
  }

  const float* wb0 = Whh + (size_t)(0*H_ + j)*H_ + q*4;
  const float* wb1 = Whh + (size_t)(1*H_ + j)*H_ + q*4;
  const float* wb2 = Whh + (size_t)(2*H_ + j)*H_ + q*4;
  const float* wb3 = Whh + (size_t)(3*H_ + j)*H_ + q*4;

  for (int s = 0; s < nsteps; ++s) {
    const int t = t0 + s;
    const unsigned ut = (unsigned)t;

    // ---- probe 8 tagged words (lane + 64k): coalesced, wave-uniform exit ----
    {
      const unsigned long long* src =
          hb2 + ((size_t)(t & 1))*(B_*H_) + (size_t)b*H_ + lane;
      float hv[8];
      unsigned pend = 0xFFu;
      do {
        #pragma unroll
        for (int k = 0; k < 8; ++k) {
          if (pend & (1u << k)) {
            unsigned long long v = __hip_atomic_load(src + 64*k,
                __ATOMIC_RELAXED, __HIP_MEMORY_SCOPE_AGENT);
            if ((unsigned)(v >> 32) == ut) {
              union { unsigned u; float f; } cv; cv.u = (unsigned)v;
              hv[k] = cv.f;
              pend &= ~(1u << k);
            }
          }
        }
      } while (!__all(pend == 0));
      // stage into this wave's private region (stride-1 writes, conflict-free)
      #pragma unroll
      for (int k = 0; k < 8; ++k) hws[wave][lane + 64*k] = hv[k];
      __builtin_amdgcn_wave_barrier();   // pin write->read order (wave-local)
    }

    // ---- FMA: 4 gates x 8 float4; weights stream from L2 (overlaps) ----
    float a0=0.f, a1=0.f, a2=0.f, a3=0.f;
    #pragma unroll
    for (int k = 0; k < 8; ++k) {
      float4 h4 = *(const float4*)&hws[wave][q*4 + 64*k];
      float4 w0 = *(const float4*)(wb0 + 64*k);
      float4 w1 = *(const float4*)(wb1 + 64*k);
      float4 w2 = *(const float4*)(wb2 + 64*k);
      float4 w3 = *(const float4*)(wb3 + 64*k);
      a0 = fmaf(w0.x,h4.x, fmaf(w0.y,h4.y, fmaf(w0.z,h4.z, fmaf(w0.w,h4.w, a0))));
      a1 = fmaf(w1.x,h4.x, fmaf(w1.y,h4.y, fmaf(w1.z,h4.z, fmaf(w1.w,h4.w, a1))));
      a2 = fmaf(w2.x,h4.x, fmaf(w2.y,h4.y, fmaf(w2.z,h4.z, fmaf(w2.w,h4.w, a2))));
      a3 = fmaf(w3.x,h4.x, fmaf(w3.y,h4.y, fmaf(w3.z,h4.z, fmaf(w3.w,h4.w, a3))));
    }
    // reduce across the 16-lane cluster (in-wave)
    #pragma unroll
    for (int msk = 1; msk < 16; msk <<= 1) {
      a0 += __shfl_xor(a0, msk, 64);
      a1 += __shfl_xor(a1, msk, 64);
      a2 += __shfl_xor(a2, msk, 64);
      a3 += __shfl_xor(a3, msk, 64);
    }

    // ---- activation + publish on lane q==0 (all in registers) ----
    if (q == 0) {
      float g0 = a0 + xv0, g1 = a1 + xv1, g2 = a2 + xv2, g3 = a3 + xv3;
      cc = sigm(g1)*cc + sigm(g0)*ftanh(g2);
      float hn = sigm(g3)*ftanh(cc);
      union { float f; unsigned u; } hu; hu.f = hn;
      unsigned long long wv =
          (((unsigned long long)(ut + 1u)) << 32) | (unsigned long long)hu.u;
      __hip_atomic_store(hb2 + ((size_t)((t+1) & 1))*(B_*H_) + (size_t)b*H_ + j, wv,
                         __ATOMIC_RELAXED, __HIP_MEMORY_SCOPE_AGENT);
      enc_out[((size_t)b*L_ + t)*H_ + j] = hn;
      if (t == L_ - 1) hT[b*H_ + j] = hn;
      // prefetch next step's Xp slice into registers (hidden under next probe)
      if (s + 1 < nsteps) {
        const float* xpn = Xp + ((size_t)(b*CL_ + s + 1))*G4_ + j;
        xv0 = xpn[0]; xv1 = xpn[H_]; xv2 = xpn[2*H_]; xv3 = xpn[3*H_];
      }
    }
  }
  if (q == 0) cbuf[b*H_ + j] = cc;
}

// ---------------------------------------------------------------------------
// out[b][n] = act( x1[b].W1[n,:K1] + (x2? x2[b].W2[n,:K2]) + bias1[n] (+bias2) )
// ---------------------------------------------------------------------------
__global__ __launch_bounds__(256) void dual_mv(
    const float* __restrict__ x1, const float* __restrict__ W1, int ld1, int K1,
    const float* __restrict__ x2, const float* __restrict__ W2, int ld2, int K2,
    const float* __restrict__ bias1, const float* __restrict__ bias2,
    float* __restrict__ out, int N, int act)
{
  const int w = blockIdx.x*4 + (threadIdx.x>>6);
  const int lane = threadIdx.x & 63;
  const int b = w / N, n = w % N;
  float s = 0.0f;
  for (int k = lane*4; k < K1; k += 256) {
    float4 xv = *(const float4*)(x1 + (size_t)b*K1 + k);
    float4 wv = *(const float4*)(W1 + (size_t)n*ld1 + k);
    s += xv.x*wv.x + xv.y*wv.y + xv.z*wv.z + xv.w*wv.w;
  }
  if (x2) {
    for (int k = lane*4; k < K2; k += 256) {
      float4 xv = *(const float4*)(x2 + (size_t)b*K2 + k);
      float4 wv = *(const float4*)(W2 + (size_t)n*ld2 + k);
      s += xv.x*wv.x + xv.y*wv.y + xv.z*wv.z + xv.w*wv.w;
    }
  }
  #pragma unroll
  for (int m=32; m>0; m>>=1) s += __shfl_xor(s, m, 64);
  if (lane == 0) {
    float r = s + bias1[n] + (bias2 ? bias2[n] : 0.0f);
    if (act) r = tanhf(r);
    out[(size_t)b*N + n] = r;
  }
}

__global__ void dec_cell(const float* __restrict__ g, float* __restrict__ c,
                         float* __restrict__ ht)
{
  int i = blockIdx.x*256 + threadIdx.x;     // 4096 threads
  int b = i >> 9, j = i & 511;
  const float* gb = g + (size_t)b*G4_;
  float gi_ = gb[j], gf = gb[H_+j], gg = gb[2*H_+j], go = gb[3*H_+j];
  float cc = c[i];
  cc = sigm(gf)*cc + sigm(gi_)*tanhf(gg);
  ht[i] = sigm(go)*tanhf(cc);
  c[i]  = cc;
}

__global__ __launch_bounds__(256) void dec_att(
    const float* __restrict__ inp, const float* __restrict__ ctx,
    const float* __restrict__ V, float* __restrict__ att)
{
  const int w = blockIdx.x*4 + (threadIdx.x>>6);  // w = b*L_ + l
  const int lane = threadIdx.x & 63;
  const int b = w >> 11;
  const float* cr = ctx + (size_t)w*H_;
  const float* ip = inp + (size_t)b*H_;
  float s = 0.0f;
  #pragma unroll
  for (int i=0;i<2;++i) {
    int k = lane*4 + i*256;
    float4 c4 = *(const float4*)(cr+k);
    float4 i4 = *(const float4*)(ip+k);
    float4 v4 = *(const float4*)(V+k);
    s += v4.x*tanhf(i4.x+c4.x) + v4.y*tanhf(i4.y+c4.y)
       + v4.z*tanhf(i4.z+c4.z) + v4.w*tanhf(i4.w+c4.w);
  }
  #pragma unroll
  for (int m=32; m>0; m>>=1) s += __shfl_xor(s, m, 64);
  if (lane == 0) att[w] = s;
}

__global__ __launch_bounds__(256) void dec_softmax(
    const float* __restrict__ att, const float* __restrict__ enc,
    int iter, int* __restrict__ chosen,
    float* __restrict__ out_alpha, float* __restrict__ out_ptr,
    float* __restrict__ x_next)
{
  const int b = blockIdx.x, tid = threadIdx.x;
  __shared__ float rv[256]; __shared__ int ri[256];
  __shared__ float s_mx, s_sum; __shared__ int s_idx;
  const int banned = iter ? chosen[b] : -1;
  float a[8]; float mx = -INFINITY;
  #pragma unroll
  for (int i=0;i<8;++i) {
    int l = (i<<8)+tid;
    float v = att[(size_t)b*L_ + l];
    if (l == banned) v = -INFINITY;
    a[i] = v; mx = fmaxf(mx, v);
  }
  rv[tid]=mx; __syncthreads();
  for (int s=128;s>0;s>>=1){ if (tid<s) rv[tid]=fmaxf(rv[tid],rv[tid+s]); __syncthreads(); }
  if (tid==0) s_mx = rv[0];
  __syncthreads();
  const float MX = s_mx;
  __syncthreads();
  float sum = 0.0f;
  #pragma unroll
  for (int i=0;i<8;++i) {
    int l = (i<<8)+tid;
    float pexp = (l == banned) ? 0.0f : expf(a[i]-MX);
    sum += pexp; a[i] = pexp;
  }
  rv[tid]=sum; __syncthreads();
  for (int s=128;s>0;s>>=1){ if (tid<s) rv[tid]+=rv[tid+s]; __syncthreads(); }
  if (tid==0) s_sum = rv[0];
  __syncthreads();
  const float inv = 1.0f/s_sum;
  __syncthreads();
  // argmax (first-occurrence on ties, matches jnp.argmax)
  float vb = -1.0f; int ib = 1<<30;
  #pragma unroll
  for (int i=0;i<8;++i) {
    int l = (i<<8)+tid;
    if (l != banned) { float v = a[i]; if (v > vb || (v == vb && l < ib)) { vb=v; ib=l; } }
  }
  rv[tid]=vb; ri[tid]=ib; __syncthreads();
  for (int s=128;s>0;s>>=1) {
    if (tid<s) {
      float v2=rv[tid+s]; int i2=ri[tid+s];
      if (v2 > rv[tid] || (v2 == rv[tid] && i2 < ri[tid])) { rv[tid]=v2; ri[tid]=i2; }
    }
    __syncthreads();
  }
  if (tid==0) {
    s_idx = ri[0];
    out_ptr[b*2+iter] = (float)ri[0];
    if (iter==0) chosen[b] = ri[0];
  }
  __syncthreads();
  #pragma unroll
  for (int i=0;i<8;++i) {
    int l = (i<<8)+tid;
    out_alpha[((size_t)b*2+iter)*L_ + l] = a[i]*inv;
  }
  const int idx = s_idx;
  for (int j=tid; j<H_; j+=256)
    x_next[(size_t)b*H_ + j] = enc[((size_t)b*L_ + idx)*H_ + j];
}

__global__ void dec_hidden1(const float* __restrict__ ctx, const float* __restrict__ alpha_all,
                            int iter, float* __restrict__ part)
{
  const int b = blockIdx.x >> 4, ch = blockIdx.x & 15;
  const int j = threadIdx.x;  // 512
  const float* al = alpha_all + ((size_t)b*2+iter)*L_ + ch*128;
  const float* cp = ctx + ((size_t)b*L_ + ch*128)*H_ + j;
  float s = 0.0f;
  for (int l=0; l<128; ++l) s += cp[(size_t)l*H_] * al[l];
  part[((size_t)b*16+ch)*H_ + j] = s;
}

__global__ void dec_hidden2(const float* __restrict__ part, float* __restrict__ hid)
{
  int i = blockIdx.x*256 + threadIdx.x;  // 4096
  int b = i >> 9, j = i & 511;
  float s = 0.0f;
  #pragma unroll
  for (int ch=0; ch<16; ++ch) s += part[((size_t)b*16+ch)*H_ + j];
  hid[i] = s;
}

// ---------------------------------------------------------------------------
extern "C" void kernel_launch(void* const* d_in, const int* in_sizes, int n_in,
                              void* d_out, int out_size, void* d_ws, size_t ws_size,
                              hipStream_t stream)
{
  const float* emb   = (const float*)d_in[0];
  const float* x0    = (const float*)d_in[1];
  const float* W_ih  = (const float*)d_in[2];
  const float* W_hh  = (const float*)d_in[3];
  const float* b_ih  = (const float*)d_in[4];
  const float* b_hh  = (const float*)d_in[5];
  const float* Wd_in = (const float*)d_in[6];
  const float* bd_in = (const float*)d_in[7];
  const float* Wd_hh = (const float*)d_in[8];
  const float* bd_hh = (const float*)d_in[9];
  const float* W_inp = (const float*)d_in[10];
  const float* b_inp = (const float*)d_in[11];
  const float* Wc    = (const float*)d_in[12];
  const float* bc    = (const float*)d_in[13];
  const float* V     = (const float*)d_in[14];
  const float* W_out = (const float*)d_in[15];
  const float* b_out = (const float*)d_in[16];

  float* ws  = (float*)d_ws;
  float* XP  = ws;                              // 8,388,608 floats (chunk Xproj)
  float* CTX = ws;                              // reused after recurrence
  float* ENC = XP + (size_t)8388608;            // 8,388,608 floats
  unsigned long long* HB2 = (unsigned long long*)(ENC + (size_t)8388608); // 8192 u64
  float* HB  = (float*)(HB2 + 8192);            // 4096 (h_T)
  float* CB  = HB + 4096;                       // 4096 (c state)
  float* DG  = CB + 4096;                       // 16384
  float* HT  = DG + 16384;                      // 4096
  float* INP = HT + 4096;                       // 4096
  float* ATT = INP + 4096;                      // 16384
  float* HID = ATT + 16384;                     // 4096
  float* XN  = HID + 4096;                      // 4096
  float* HD  = XN + 4096;                       // 4096
  float* PART = HD + 4096;                      // 65536
  int* CHOSEN = (int*)(PART + 65536);           // 8

  // zero tagged h buffer (tag0 = h0=0), h_T, c0 — contiguous region
  hipMemsetAsync(HB2, 0, 8192*sizeof(unsigned long long) + (4096+4096)*sizeof(float), stream);

  // ---- encoder: chunked Xproj GEMM + barrier-free dataflow recurrence ----
  for (int c=0; c<4; ++c) {
    gemm128<<<dim3(G4_/128, (B_*CL_)/128), 256, 0, stream>>>(
        emb, W_ih, b_ih, b_hh, XP, B_*CL_, G4_, E_, CL_, L_, c*CL_);
    recur11<<<256, 256, 0, stream>>>(XP, W_hh, ENC, HB2, CB, HB, c*CL_, CL_);
  }
  // ---- ctx = enc_out @ Wc^T + bc  (reuses XP region) ----
  gemm128<<<dim3(H_/128, (B_*L_)/128), 256, 0, stream>>>(
      ENC, Wc, bc, nullptr, CTX, B_*L_, H_, H_, L_, L_, 0);

  // ---- decoder: 2 pointer steps ----
  float* out = (float*)d_out;
  const float* x_cur = x0;
  const float* h_cur = HB;
  for (int iter=0; iter<2; ++iter) {
    dual_mv<<<(B_*G4_)/4, 256, 0, stream>>>(x_cur, Wd_in, H_, H_,
                                            h_cur, Wd_hh, H_, H_,
                                            bd_in, bd_hh, DG, G4_, 0);
    dec_cell<<<16, 256, 0, stream>>>(DG, CB, HT);
    dual_mv<<<(B_*H_)/4, 256, 0, stream>>>(HT, W_inp, H_, H_,
                                           nullptr, nullptr, 0, 0,
                                           b_inp, nullptr, INP, H_, 0);
    dec_att<<<(B_*L_)/4, 256, 0, stream>>>(INP, CTX, V, ATT);
    dec_softmax<<<B_, 256, 0, stream>>>(ATT, ENC, iter, CHOSEN, out, out + 32768, XN);
    dec_hidden1<<<B_*16, 512, 0, stream>>>(CTX, out, iter, PART);
    dec_hidden2<<<16, 256, 0, stream>>>(PART, HID);
    dual_mv<<<(B_*H_)/4, 256, 0, stream>>>(HID, W_out, 2*H_, H_,
                                           HT, W_out + H_, 2*H_, H_,
                                           b_out, nullptr, HD, H_, 1);
    x_cur = XN; h_cur = HD;
  }
}

// Round 12
// 8429.261 us; speedup vs baseline: 1.5068x; 1.0770x over previous
//
#include <hip/hip_runtime.h>
#include <math.h>

#define B_   8
#define L_   2048
#define E_   768
#define H_   512
#define G4_  2048   // 4*H
#define CL_  512    // L chunk length

static __device__ __forceinline__ float sigm(float x){ return 1.0f/(1.0f+expf(-x)); }
static __device__ __forceinline__ float ftanh(float x){
  float ax = fabsf(x);
  float e  = expf(2.0f*ax);            // inf for large ax -> r = 1
  float r  = 1.0f - 2.0f/(e+1.0f);
  return copysignf(r, x);
}

// ---------------------------------------------------------------------------
// GEMM body: C[crow(r)][N] = A'[r,:K] . W[n,:K]^T + bias1 (+bias2)
// A row map: ab=r/CL, al=r%CL, arow=ab*Ltot+c0+al  (batch-chunk gather)
// C row map: cb=r/CLc, cl=r%CLc, crow=cb*Ltotc+c0c+cl (scatter for partial L)
// 128x128 tile, BK=16, 256 threads, 8x8 micro tile.
// ---------------------------------------------------------------------------
__device__ __forceinline__ void gemm_body(
    const float* __restrict__ A, const float* __restrict__ W,
    const float* __restrict__ bias1, const float* __restrict__ bias2,
    float* __restrict__ C, int N, int K, int CL, int Ltot, int c0,
    int CLc, int Ltotc, int c0c, int bm, int bn)
{
  __shared__ float As[16][132];
  __shared__ float Bs[16][132];
  const int tid = threadIdx.x;

  const int r  = tid >> 1;          // 0..127 (loader row)
  const int kq = (tid & 1) * 8;     // 0 or 8 (loader k-offset)
  const int am = bm + r;
  const int ab = am / CL, al = am % CL;
  const float* Arow = A + ((size_t)ab * Ltot + c0 + al) * K;
  const float* Wrow = W + (size_t)(bn + r) * K;

  const int tx = tid & 15, ty = tid >> 4;
  float acc[8][8] = {};

  for (int k0 = 0; k0 < K; k0 += 16) {
    float4 a0 = *(const float4*)(Arow + k0 + kq);
    float4 a1 = *(const float4*)(Arow + k0 + kq + 4);
    float4 w0 = *(const float4*)(Wrow + k0 + kq);
    float4 w1 = *(const float4*)(Wrow + k0 + kq + 4);
    __syncthreads();
    As[kq+0][r]=a0.x; As[kq+1][r]=a0.y; As[kq+2][r]=a0.z; As[kq+3][r]=a0.w;
    As[kq+4][r]=a1.x; As[kq+5][r]=a1.y; As[kq+6][r]=a1.z; As[kq+7][r]=a1.w;
    Bs[kq+0][r]=w0.x; Bs[kq+1][r]=w0.y; Bs[kq+2][r]=w0.z; Bs[kq+3][r]=w0.w;
    Bs[kq+4][r]=w1.x; Bs[kq+5][r]=w1.y; Bs[kq+6][r]=w1.z; Bs[kq+7][r]=w1.w;
    __syncthreads();
    #pragma unroll
    for (int k = 0; k < 16; ++k) {
      float4 x0 = *(const float4*)&As[k][ty*4];
      float4 x1 = *(const float4*)&As[k][64 + ty*4];
      float4 y0 = *(const float4*)&Bs[k][tx*4];
      float4 y1 = *(const float4*)&Bs[k][64 + tx*4];
      float av[8] = {x0.x,x0.y,x0.z,x0.w, x1.x,x1.y,x1.z,x1.w};
      float bv[8] = {y0.x,y0.y,y0.z,y0.w, y1.x,y1.y,y1.z,y1.w};
      #pragma unroll
      for (int i=0;i<8;++i)
        #pragma unroll
        for (int j=0;j<8;++j)
          acc[i][j] += av[i]*bv[j];
    }
  }

  float bs[8];
  #pragma unroll
  for (int j=0;j<4;++j) {
    int c0n = bn + tx*4 + j, c1n = bn + 64 + tx*4 + j;
    bs[j]   = bias1[c0n] + (bias2 ? bias2[c0n] : 0.0f);
    bs[4+j] = bias1[c1n] + (bias2 ? bias2[c1n] : 0.0f);
  }
  #pragma unroll
  for (int i=0;i<8;++i) {
    int r0 = bm + ((i<4) ? (ty*4+i) : (64 + ty*4 + (i-4)));
    int cb = r0 / CLc, cl = r0 % CLc;
    size_t crow = (size_t)cb * Ltotc + c0c + cl;
    float4 o0 = { acc[i][0]+bs[0], acc[i][1]+bs[1], acc[i][2]+bs[2], acc[i][3]+bs[3] };
    float4 o1 = { acc[i][4]+bs[4], acc[i][5]+bs[5], acc[i][6]+bs[6], acc[i][7]+bs[7] };
    *(float4*)&C[crow*N + bn + tx*4]      = o0;
    *(float4*)&C[crow*N + bn + 64 + tx*4] = o1;
  }
}

__global__ __launch_bounds__(256) void gemm128(
    const float* __restrict__ A, const float* __restrict__ W,
    const float* __restrict__ bias1, const float* __restrict__ bias2,
    float* __restrict__ C, int N, int K, int CL, int Ltot, int c0,
    int CLc, int Ltotc, int c0c)
{
  gemm_body(A, W, bias1, bias2, C, N, K, CL, Ltot, c0, CLc, Ltotc, c0c,
            blockIdx.y*128, blockIdx.x*128);
}

// ---------------------------------------------------------------------------
// Recurrence body = r5 champion VERBATIM (measured 1245 us/dispatch,
// 2.43 us/step — best of 7 protocol variants r2..r11; MALL-RT-bound).
// Block (b = bid>>5, m = bid&31) owns batch b, h-indices [m*16,m*16+16).
// 16-lane cluster c owns all 4 gates of h-index m*16+c; weights stream from
// per-XCD L2 (overlaps poll; LDS-resident weights measured SLOWER r6/r8/r9).
// Tagged u64 exchange (tag=t+1 | h bits) via relaxed agent atomics; tag==t
// self-validating, no fences; parity double-buffered LDS staging; self-
// bypass of own words; ONE __syncthreads per step.
// ---------------------------------------------------------------------------
__device__ __forceinline__ void recur_body(
    const float* __restrict__ Xp, const float* __restrict__ Whh,
    float* __restrict__ enc_out, unsigned long long* __restrict__ hb2,
    float* __restrict__ cbuf, float* __restrict__ hT, int t0, int nsteps)
{
  const int tid = threadIdx.x;
  const int b   = blockIdx.x >> 5;     // batch 0..7
  const int m   = blockIdx.x & 31;     // h-slice 0..31
  const int c   = tid >> 4;            // cluster 0..15
  const int q   = tid & 15;            // lane within cluster
  const int j   = m*16 + c;            // owned h index

  __shared__ float hsh[2][512];
  __shared__ float xpsh[2][64];

  // weights: 4 gates x 1 row x 32 cols per thread (compiler streams via L2)
  float4 w4[4][8];
  #pragma unroll
  for (int gi = 0; gi < 4; ++gi) {
    const float* wr = Whh + ((size_t)(gi*H_ + j))*H_ + q*4;
    #pragma unroll
    for (int k = 0; k < 8; ++k) w4[gi][k] = *(const float4*)(wr + k*64);
  }
  float cc = 0.0f;
  if (q == 0) cc = cbuf[b*H_ + j];

  float xv = 0.0f;
  if (tid < 64)
    xv = Xp[((size_t)(b*CL_ + 0))*G4_ + (size_t)(tid>>4)*H_ + m*16 + (tid&15)];

  const bool own = ((tid >> 3) == m);  // this thread's 2 words are block-own

  for (int s = 0; s < nsteps; ++s) {
    const int t = t0 + s;
    const int p = s & 1;

    if (tid < 64) {
      xpsh[p][tid] = xv;
      if (s + 1 < nsteps)
        xv = Xp[((size_t)(b*CL_ + s + 1))*G4_ + (size_t)(tid>>4)*H_ + m*16 + (tid&15)];
    }

    if (!(own && s > 0)) {
      const unsigned long long* src =
          hb2 + ((size_t)(t & 1))*(B_*H_) + (size_t)b*H_ + tid*2;
      unsigned long long v0 = 0, v1 = 0;
      bool d0 = false, d1 = false;
      do {
        if (!d0) v0 = __hip_atomic_load(src,   __ATOMIC_RELAXED, __HIP_MEMORY_SCOPE_AGENT);
        if (!d1) v1 = __hip_atomic_load(src+1, __ATOMIC_RELAXED, __HIP_MEMORY_SCOPE_AGENT);
        d0 = d0 || ((unsigned)(v0 >> 32) == (unsigned)t);
        d1 = d1 || ((unsigned)(v1 >> 32) == (unsigned)t);
      } while (!(d0 && d1));
      union { unsigned u; float f; } a0u, a1u;
      a0u.u = (unsigned)v0; a1u.u = (unsigned)v1;
      hsh[p][2*tid]   = a0u.f;
      hsh[p][2*tid+1] = a1u.f;
    }
    __syncthreads();                               // the ONLY per-step barrier

    float xg0=0.f, xg1=0.f, xg2=0.f, xg3=0.f;
    if (q == 0) {
      xg0 = xpsh[p][c];      xg1 = xpsh[p][16+c];
      xg2 = xpsh[p][32+c];   xg3 = xpsh[p][48+c];
    }

    float a0=0.f, a1=0.f, a2=0.f, a3=0.f;
    #pragma unroll
    for (int k = 0; k < 8; ++k) {
      float4 h4 = *(const float4*)&hsh[p][q*4 + k*64];
      a0 = fmaf(w4[0][k].x,h4.x, fmaf(w4[0][k].y,h4.y, fmaf(w4[0][k].z,h4.z, fmaf(w4[0][k].w,h4.w, a0))));
      a1 = fmaf(w4[1][k].x,h4.x, fmaf(w4[1][k].y,h4.y, fmaf(w4[1][k].z,h4.z, fmaf(w4[1][k].w,h4.w, a1))));
      a2 = fmaf(w4[2][k].x,h4.x, fmaf(w4[2][k].y,h4.y, fmaf(w4[2][k].z,h4.z, fmaf(w4[2][k].w,h4.w, a2))));
      a3 = fmaf(w4[3][k].x,h4.x, fmaf(w4[3][k].y,h4.y, fmaf(w4[3][k].z,h4.z, fmaf(w4[3][k].w,h4.w, a3))));
    }
    #pragma unroll
    for (int msk = 1; msk < 16; msk <<= 1) {
      a0 += __shfl_xor(a0, msk, 64);
      a1 += __shfl_xor(a1, msk, 64);
      a2 += __shfl_xor(a2, msk, 64);
      a3 += __shfl_xor(a3, msk, 64);
    }

    if (q == 0) {
      float g0 = a0 + xg0, g1 = a1 + xg1, g2 = a2 + xg2, g3 = a3 + xg3;
      cc = sigm(g1)*cc + sigm(g0)*ftanh(g2);
      float hn = sigm(g3)*ftanh(cc);
      union { float f; unsigned u; } hu; hu.f = hn;
      unsigned long long wv =
          (((unsigned long long)(unsigned)(t + 1)) << 32) | (unsigned long long)hu.u;
      __hip_atomic_store(hb2 + ((size_t)((t+1) & 1))*(B_*H_) + (size_t)b*H_ + j, wv,
                         __ATOMIC_RELAXED, __HIP_MEMORY_SCOPE_AGENT);
      hsh[p^1][j] = hn;                  // self-bypass for next step
      enc_out[((size_t)b*L_ + t)*H_ + j] = hn;
      if (t == L_ - 1) hT[b*H_ + j] = hn;
    }
  }
  if (q == 0) cbuf[b*H_ + j] = cc;
}

// ---------------------------------------------------------------------------
// Fused launch: blocks [0,256) = recurrence chunk; blocks [256,256+ngemm) =
// concurrent GEMM (next chunk's Xproj, or ctx for finalized ENC rows).
// Recur is latency-bound (VALUBusy 21%) -> GEMM rides the idle SIMD slots.
// Recur blocks have the lowest IDs (dispatched resident first); GEMM blocks
// never wait on recur -> no deadlock possible, worst case lost overlap.
// ---------------------------------------------------------------------------
__global__ __launch_bounds__(256, 4) void fused_rg(
    const float* __restrict__ Xp, const float* __restrict__ Whh,
    float* __restrict__ enc_out, unsigned long long* __restrict__ hb2,
    float* __restrict__ cbuf, float* __restrict__ hT, int t0, int nsteps,
    const float* __restrict__ A, const float* __restrict__ W,
    const float* __restrict__ bias1, const float* __restrict__ bias2,
    float* __restrict__ C, int gN, int gK, int gCL, int gLtot, int gc0,
    int gCLc, int gLtotc, int gc0c, int gbx)
{
  if ((int)blockIdx.x < 256) {
    recur_body(Xp, Whh, enc_out, hb2, cbuf, hT, t0, nsteps);
  } else {
    const int b2 = (int)blockIdx.x - 256;
    gemm_body(A, W, bias1, bias2, C, gN, gK, gCL, gLtot, gc0,
              gCLc, gLtotc, gc0c, (b2 / gbx) * 128, (b2 % gbx) * 128);
  }
}

// ---------------------------------------------------------------------------
// out[b][n] = act( x1[b].W1[n,:K1] + (x2? x2[b].W2[n,:K2]) + bias1[n] (+bias2) )
// ---------------------------------------------------------------------------
__global__ __launch_bounds__(256) void dual_mv(
    const float* __restrict__ x1, const float* __restrict__ W1, int ld1, int K1,
    const float* __restrict__ x2, const float* __restrict__ W2, int ld2, int K2,
    const float* __restrict__ bias1, const float* __restrict__ bias2,
    float* __restrict__ out, int N, int act)
{
  const int w = blockIdx.x*4 + (threadIdx.x>>6);
  const int lane = threadIdx.x & 63;
  const int b = w / N, n = w % N;
  float s = 0.0f;
  for (int k = lane*4; k < K1; k += 256) {
    float4 xv = *(const float4*)(x1 + (size_t)b*K1 + k);
    float4 wv = *(const float4*)(W1 + (size_t)n*ld1 + k);
    s += xv.x*wv.x + xv.y*wv.y + xv.z*wv.z + xv.w*wv.w;
  }
  if (x2) {
    for (int k = lane*4; k < K2; k += 256) {
      float4 xv = *(const float4*)(x2 + (size_t)b*K2 + k);
      float4 wv = *(const float4*)(W2 + (size_t)n*ld2 + k);
      s += xv.x*wv.x + xv.y*wv.y + xv.z*wv.z + xv.w*wv.w;
    }
  }
  #pragma unroll
  for (int m=32; m>0; m>>=1) s += __shfl_xor(s, m, 64);
  if (lane == 0) {
    float r = s + bias1[n] + (bias2 ? bias2[n] : 0.0f);
    if (act) r = tanhf(r);
    out[(size_t)b*N + n] = r;
  }
}

__global__ void dec_cell(const float* __restrict__ g, float* __restrict__ c,
                         float* __restrict__ ht)
{
  int i = blockIdx.x*256 + threadIdx.x;     // 4096 threads
  int b = i >> 9, j = i & 511;
  const float* gb = g + (size_t)b*G4_;
  float gi_ = gb[j], gf = gb[H_+j], gg = gb[2*H_+j], go = gb[3*H_+j];
  float cc = c[i];
  cc = sigm(gf)*cc + sigm(gi_)*tanhf(gg);
  ht[i] = sigm(go)*tanhf(cc);
  c[i]  = cc;
}

__global__ __launch_bounds__(256) void dec_att(
    const float* __restrict__ inp, const float* __restrict__ ctx,
    const float* __restrict__ V, float* __restrict__ att)
{
  const int w = blockIdx.x*4 + (threadIdx.x>>6);  // w = b*L_ + l
  const int lane = threadIdx.x & 63;
  const int b = w >> 11;
  const float* cr = ctx + (size_t)w*H_;
  const float* ip = inp + (size_t)b*H_;
  float s = 0.0f;
  #pragma unroll
  for (int i=0;i<2;++i) {
    int k = lane*4 + i*256;
    float4 c4 = *(const float4*)(cr+k);
    float4 i4 = *(const float4*)(ip+k);
    float4 v4 = *(const float4*)(V+k);
    s += v4.x*tanhf(i4.x+c4.x) + v4.y*tanhf(i4.y+c4.y)
       + v4.z*tanhf(i4.z+c4.z) + v4.w*tanhf(i4.w+c4.w);
  }
  #pragma unroll
  for (int m=32; m>0; m>>=1) s += __shfl_xor(s, m, 64);
  if (lane == 0) att[w] = s;
}

__global__ __launch_bounds__(256) void dec_softmax(
    const float* __restrict__ att, const float* __restrict__ enc,
    int iter, int* __restrict__ chosen,
    float* __restrict__ out_alpha, float* __restrict__ out_ptr,
    float* __restrict__ x_next)
{
  const int b = blockIdx.x, tid = threadIdx.x;
  __shared__ float rv[256]; __shared__ int ri[256];
  __shared__ float s_mx, s_sum; __shared__ int s_idx;
  const int banned = iter ? chosen[b] : -1;
  float a[8]; float mx = -INFINITY;
  #pragma unroll
  for (int i=0;i<8;++i) {
    int l = (i<<8)+tid;
    float v = att[(size_t)b*L_ + l];
    if (l == banned) v = -INFINITY;
    a[i] = v; mx = fmaxf(mx, v);
  }
  rv[tid]=mx; __syncthreads();
  for (int s=128;s>0;s>>=1){ if (tid<s) rv[tid]=fmaxf(rv[tid],rv[tid+s]); __syncthreads(); }
  if (tid==0) s_mx = rv[0];
  __syncthreads();
  const float MX = s_mx;
  __syncthreads();
  float sum = 0.0f;
  #pragma unroll
  for (int i=0;i<8;++i) {
    int l = (i<<8)+tid;
    float pexp = (l == banned) ? 0.0f : expf(a[i]-MX);
    sum += pexp; a[i] = pexp;
  }
  rv[tid]=sum; __syncthreads();
  for (int s=128;s>0;s>>=1){ if (tid<s) rv[tid]+=rv[tid+s]; __syncthreads(); }
  if (tid==0) s_sum = rv[0];
  __syncthreads();
  const float inv = 1.0f/s_sum;
  __syncthreads();
  // argmax (first-occurrence on ties, matches jnp.argmax)
  float vb = -1.0f; int ib = 1<<30;
  #pragma unroll
  for (int i=0;i<8;++i) {
    int l = (i<<8)+tid;
    if (l != banned) { float v = a[i]; if (v > vb || (v == vb && l < ib)) { vb=v; ib=l; } }
  }
  rv[tid]=vb; ri[tid]=ib; __syncthreads();
  for (int s=128;s>0;s>>=1) {
    if (tid<s) {
      float v2=rv[tid+s]; int i2=ri[tid+s];
      if (v2 > rv[tid] || (v2 == rv[tid] && i2 < ri[tid])) { rv[tid]=v2; ri[tid]=i2; }
    }
    __syncthreads();
  }
  if (tid==0) {
    s_idx = ri[0];
    out_ptr[b*2+iter] = (float)ri[0];
    if (iter==0) chosen[b] = ri[0];
  }
  __syncthreads();
  #pragma unroll
  for (int i=0;i<8;++i) {
    int l = (i<<8)+tid;
    out_alpha[((size_t)b*2+iter)*L_ + l] = a[i]*inv;
  }
  const int idx = s_idx;
  for (int j=tid; j<H_; j+=256)
    x_next[(size_t)b*H_ + j] = enc[((size_t)b*L_ + idx)*H_ + j];
}

__global__ void dec_hidden1(const float* __restrict__ ctx, const float* __restrict__ alpha_all,
                            int iter, float* __restrict__ part)
{
  const int b = blockIdx.x >> 4, ch = blockIdx.x & 15;
  const int j = threadIdx.x;  // 512
  const float* al = alpha_all + ((size_t)b*2+iter)*L_ + ch*128;
  const float* cp = ctx + ((size_t)b*L_ + ch*128)*H_ + j;
  float s = 0.0f;
  for (int l=0; l<128; ++l) s += cp[(size_t)l*H_] * al[l];
  part[((size_t)b*16+ch)*H_ + j] = s;
}

__global__ void dec_hidden2(const float* __restrict__ part, float* __restrict__ hid)
{
  int i = blockIdx.x*256 + threadIdx.x;  // 4096
  int b = i >> 9, j = i & 511;
  float s = 0.0f;
  #pragma unroll
  for (int ch=0; ch<16; ++ch) s += part[((size_t)b*16+ch)*H_ + j];
  hid[i] = s;
}

// ---------------------------------------------------------------------------
extern "C" void kernel_launch(void* const* d_in, const int* in_sizes, int n_in,
                              void* d_out, int out_size, void* d_ws, size_t ws_size,
                              hipStream_t stream)
{
  const float* emb   = (const float*)d_in[0];
  const float* x0    = (const float*)d_in[1];
  const float* W_ih  = (const float*)d_in[2];
  const float* W_hh  = (const float*)d_in[3];
  const float* b_ih  = (const float*)d_in[4];
  const float* b_hh  = (const float*)d_in[5];
  const float* Wd_in = (const float*)d_in[6];
  const float* bd_in = (const float*)d_in[7];
  const float* Wd_hh = (const float*)d_in[8];
  const float* bd_hh = (const float*)d_in[9];
  const float* W_inp = (const float*)d_in[10];
  const float* b_inp = (const float*)d_in[11];
  const float* Wc    = (const float*)d_in[12];
  const float* bc    = (const float*)d_in[13];
  const float* V     = (const float*)d_in[14];
  const float* W_out = (const float*)d_in[15];
  const float* b_out = (const float*)d_in[16];

  const size_t BIG = 8388608;  // floats per XP/ENC buffer
  const size_t tail_floats = 8192*2 /*HB2*/ + 4096 + 4096 + 16384 + 4096*4 + 16384 + 65536 + 64;
  const bool dbuf = ws_size >= (3*BIG + tail_floats) * sizeof(float);

  float* ws  = (float*)d_ws;
  float* XPA = ws;                               // 8,388,608 floats; also CTX
  float* XPB = dbuf ? (XPA + BIG) : XPA;         // second Xproj buffer
  float* ENC = (dbuf ? XPB : XPA) + BIG;         // 8,388,608 floats
  unsigned long long* HB2 = (unsigned long long*)(ENC + BIG); // 8192 u64
  float* HB  = (float*)(HB2 + 8192);             // 4096 (h_T)
  float* CB  = HB + 4096;                        // 4096 (c state)
  float* DG  = CB + 4096;                        // 16384
  float* HT  = DG + 16384;                       // 4096
  float* INP = HT + 4096;                        // 4096
  float* ATT = INP + 4096;                       // 16384
  float* HID = ATT + 16384;                      // 4096
  float* XN  = HID + 4096;                       // 4096
  float* HD  = XN + 4096;                        // 4096
  float* PART = HD + 4096;                       // 65536
  int* CHOSEN = (int*)(PART + 65536);            // 8
  float* CTX = XPA;

  // zero tagged h buffer (tag0 = h0=0), h_T, c0 — contiguous region
  hipMemsetAsync(HB2, 0, 8192*sizeof(unsigned long long) + (4096+4096)*sizeof(float), stream);

  if (dbuf) {
    // 1. Xproj chunk0 -> XPA (exposed)
    gemm128<<<dim3(G4_/128, (B_*CL_)/128), 256, 0, stream>>>(
        emb, W_ih, b_ih, b_hh, XPA, G4_, E_, CL_, L_, 0*CL_, 1<<30, 0, 0);
    // 2-4. recur(chunk c) || Xproj(chunk c+1) into the other buffer
    float* xpsrc = XPA; float* xpdst = XPB;
    for (int c = 0; c < 3; ++c) {
      fused_rg<<<256 + 512, 256, 0, stream>>>(
          xpsrc, W_hh, ENC, HB2, CB, HB, c*CL_, CL_,
          emb, W_ih, b_ih, b_hh, xpdst, G4_, E_, CL_, L_, (c+1)*CL_,
          1<<30, 0, 0, /*gbx=*/16);
      float* tmp = xpsrc; xpsrc = xpdst; xpdst = tmp;
    }
    // 5. recur(chunk3) || ctx rows l<1536 (ENC chunks 0-2 finalized) -> CTX
    fused_rg<<<256 + 384, 256, 0, stream>>>(
        xpsrc, W_hh, ENC, HB2, CB, HB, 3*CL_, CL_,
        ENC, Wc, bc, nullptr, CTX, H_, H_, 1536, L_, 0,
        1536, L_, 0, /*gbx=*/4);
    // 6. ctx rows l in [1536,2048) (exposed, small)
    gemm128<<<dim3(H_/128, (B_*CL_)/128), 256, 0, stream>>>(
        ENC, Wc, bc, nullptr, CTX, H_, H_, CL_, L_, 1536, CL_, L_, 1536);
  } else {
    // serial fallback (= r5 schedule)
    for (int c = 0; c < 4; ++c) {
      gemm128<<<dim3(G4_/128, (B_*CL_)/128), 256, 0, stream>>>(
          emb, W_ih, b_ih, b_hh, XPA, G4_, E_, CL_, L_, c*CL_, 1<<30, 0, 0);
      fused_rg<<<256, 256, 0, stream>>>(
          XPA, W_hh, ENC, HB2, CB, HB, c*CL_, CL_,
          nullptr, nullptr, nullptr, nullptr, nullptr, 0, 0, 1, 1, 0, 1, 1, 0, 1);
    }
    gemm128<<<dim3(H_/128, (B_*L_)/128), 256, 0, stream>>>(
        ENC, Wc, bc, nullptr, CTX, H_, H_, L_, L_, 0, 1<<30, 0, 0);
  }

  // ---- decoder: 2 pointer steps ----
  float* out = (float*)d_out;
  const float* x_cur = x0;
  const float* h_cur = HB;
  for (int iter=0; iter<2; ++iter) {
    dual_mv<<<(B_*G4_)/4, 256, 0, stream>>>(x_cur, Wd_in, H_, H_,
                                            h_cur, Wd_hh, H_, H_,
                                            bd_in, bd_hh, DG, G4_, 0);
    dec_cell<<<16, 256, 0, stream>>>(DG, CB, HT);
    dual_mv<<<(B_*H_)/4, 256, 0, stream>>>(HT, W_inp, H_, H_,
                                           nullptr, nullptr, 0, 0,
                                           b_inp, nullptr, INP, H_, 0);
    dec_att<<<(B_*L_)/4, 256, 0, stream>>>(INP, CTX, V, ATT);
    dec_softmax<<<B_, 256, 0, stream>>>(ATT, ENC, iter, CHOSEN, out, out + 32768, XN);
    dec_hidden1<<<B_*16, 512, 0, stream>>>(CTX, out, iter, PART);
    dec_hidden2<<<16, 256, 0, stream>>>(PART, HID);
    dual_mv<<<(B_*H_)/4, 256, 0, stream>>>(HID, W_out, 2*H_, H_,
                                           HT, W_out + H_, 2*H_, H_,
                                           b_out, nullptr, HD, H_, 1);
    x_cur = XN; h_cur = HD;
  }
}

// Round 13
// 8393.346 us; speedup vs baseline: 1.5133x; 1.0043x over previous
//
#include <hip/hip_runtime.h>
#include <math.h>

#define B_   8
#define L_   2048
#define E_   768
#define H_   512
#define G4_  2048   // 4*H
#define CL_  512    // L chunk length

static __device__ __forceinline__ float sigm(float x){ return 1.0f/(1.0f+expf(-x)); }
static __device__ __forceinline__ float ftanh(float x){
  float ax = fabsf(x);
  float e  = expf(2.0f*ax);            // inf for large ax -> r = 1
  float r  = 1.0f - 2.0f/(e+1.0f);
  return copysignf(r, x);
}

// ---------------------------------------------------------------------------
// GEMM body: C[crow(r)][N] = A'[r,:K] . W[n,:K]^T + bias1 (+bias2)
// A row map: ab=r/CL, al=r%CL, arow=ab*Ltot+c0+al  (batch-chunk gather)
// C row map: cb=r/CLc, cl=r%CLc, crow=cb*Ltotc+c0c+cl (scatter for partial L)
// 128x128 tile, BK=16, 256 threads, 8x8 micro tile.
// ---------------------------------------------------------------------------
__device__ __forceinline__ void gemm_body(
    const float* __restrict__ A, const float* __restrict__ W,
    const float* __restrict__ bias1, const float* __restrict__ bias2,
    float* __restrict__ C, int N, int K, int CL, int Ltot, int c0,
    int CLc, int Ltotc, int c0c, int bm, int bn)
{
  __shared__ float As[16][132];
  __shared__ float Bs[16][132];
  const int tid = threadIdx.x;

  const int r  = tid >> 1;          // 0..127 (loader row)
  const int kq = (tid & 1) * 8;     // 0 or 8 (loader k-offset)
  const int am = bm + r;
  const int ab = am / CL, al = am % CL;
  const float* Arow = A + ((size_t)ab * Ltot + c0 + al) * K;
  const float* Wrow = W + (size_t)(bn + r) * K;

  const int tx = tid & 15, ty = tid >> 4;
  float acc[8][8] = {};

  for (int k0 = 0; k0 < K; k0 += 16) {
    float4 a0 = *(const float4*)(Arow + k0 + kq);
    float4 a1 = *(const float4*)(Arow + k0 + kq + 4);
    float4 w0 = *(const float4*)(Wrow + k0 + kq);
    float4 w1 = *(const float4*)(Wrow + k0 + kq + 4);
    __syncthreads();
    As[kq+0][r]=a0.x; As[kq+1][r]=a0.y; As[kq+2][r]=a0.z; As[kq+3][r]=a0.w;
    As[kq+4][r]=a1.x; As[kq+5][r]=a1.y; As[kq+6][r]=a1.z; As[kq+7][r]=a1.w;
    Bs[kq+0][r]=w0.x; Bs[kq+1][r]=w0.y; Bs[kq+2][r]=w0.z; Bs[kq+3][r]=w0.w;
    Bs[kq+4][r]=w1.x; Bs[kq+5][r]=w1.y; Bs[kq+6][r]=w1.z; Bs[kq+7][r]=w1.w;
    __syncthreads();
    #pragma unroll
    for (int k = 0; k < 16; ++k) {
      float4 x0 = *(const float4*)&As[k][ty*4];
      float4 x1 = *(const float4*)&As[k][64 + ty*4];
      float4 y0 = *(const float4*)&Bs[k][tx*4];
      float4 y1 = *(const float4*)&Bs[k][64 + tx*4];
      float av[8] = {x0.x,x0.y,x0.z,x0.w, x1.x,x1.y,x1.z,x1.w};
      float bv[8] = {y0.x,y0.y,y0.z,y0.w, y1.x,y1.y,y1.z,y1.w};
      #pragma unroll
      for (int i=0;i<8;++i)
        #pragma unroll
        for (int j=0;j<8;++j)
          acc[i][j] += av[i]*bv[j];
    }
  }

  float bs[8];
  #pragma unroll
  for (int j=0;j<4;++j) {
    int c0n = bn + tx*4 + j, c1n = bn + 64 + tx*4 + j;
    bs[j]   = bias1[c0n] + (bias2 ? bias2[c0n] : 0.0f);
    bs[4+j] = bias1[c1n] + (bias2 ? bias2[c1n] : 0.0f);
  }
  #pragma unroll
  for (int i=0;i<8;++i) {
    int r0 = bm + ((i<4) ? (ty*4+i) : (64 + ty*4 + (i-4)));
    int cb = r0 / CLc, cl = r0 % CLc;
    size_t crow = (size_t)cb * Ltotc + c0c + cl;
    float4 o0 = { acc[i][0]+bs[0], acc[i][1]+bs[1], acc[i][2]+bs[2], acc[i][3]+bs[3] };
    float4 o1 = { acc[i][4]+bs[4], acc[i][5]+bs[5], acc[i][6]+bs[6], acc[i][7]+bs[7] };
    *(float4*)&C[crow*N + bn + tx*4]      = o0;
    *(float4*)&C[crow*N + bn + 64 + tx*4] = o1;
  }
}

__global__ __launch_bounds__(256) void gemm128(
    const float* __restrict__ A, const float* __restrict__ W,
    const float* __restrict__ bias1, const float* __restrict__ bias2,
    float* __restrict__ C, int N, int K, int CL, int Ltot, int c0,
    int CLc, int Ltotc, int c0c)
{
  gemm_body(A, W, bias1, bias2, C, N, K, CL, Ltot, c0, CLc, Ltotc, c0c,
            blockIdx.y*128, blockIdx.x*128);
}

// ---------------------------------------------------------------------------
// Recurrence body = r5 champion VERBATIM (measured 1245 us/dispatch,
// 2.43 us/step — best of 7 protocol variants r2..r11; MALL-RT-bound).
// Block (b = bid>>5, m = bid&31) owns batch b, h-indices [m*16,m*16+16).
// 16-lane cluster c owns all 4 gates of h-index m*16+c; weights stream from
// per-XCD L2 (overlaps poll; LDS-resident weights measured SLOWER r6/r8/r9).
// Tagged u64 exchange (tag=t+1 | h bits) via relaxed agent atomics; tag==t
// self-validating, no fences; parity double-buffered LDS staging; self-
// bypass of own words; ONE __syncthreads per step.
// ---------------------------------------------------------------------------
__device__ __forceinline__ void recur_body(
    const float* __restrict__ Xp, const float* __restrict__ Whh,
    float* __restrict__ enc_out, unsigned long long* __restrict__ hb2,
    float* __restrict__ cbuf, float* __restrict__ hT, int t0, int nsteps)
{
  const int tid = threadIdx.x;
  const int b   = blockIdx.x >> 5;     // batch 0..7
  const int m   = blockIdx.x & 31;     // h-slice 0..31
  const int c   = tid >> 4;            // cluster 0..15
  const int q   = tid & 15;            // lane within cluster
  const int j   = m*16 + c;            // owned h index

  __shared__ float hsh[2][512];
  __shared__ float xpsh[2][64];

  // weights: 4 gates x 1 row x 32 cols per thread (compiler streams via L2)
  float4 w4[4][8];
  #pragma unroll
  for (int gi = 0; gi < 4; ++gi) {
    const float* wr = Whh + ((size_t)(gi*H_ + j))*H_ + q*4;
    #pragma unroll
    for (int k = 0; k < 8; ++k) w4[gi][k] = *(const float4*)(wr + k*64);
  }
  float cc = 0.0f;
  if (q == 0) cc = cbuf[b*H_ + j];

  float xv = 0.0f;
  if (tid < 64)
    xv = Xp[((size_t)(b*CL_ + 0))*G4_ + (size_t)(tid>>4)*H_ + m*16 + (tid&15)];

  const bool own = ((tid >> 3) == m);  // this thread's 2 words are block-own

  for (int s = 0; s < nsteps; ++s) {
    const int t = t0 + s;
    const int p = s & 1;

    if (tid < 64) {
      xpsh[p][tid] = xv;
      if (s + 1 < nsteps)
        xv = Xp[((size_t)(b*CL_ + s + 1))*G4_ + (size_t)(tid>>4)*H_ + m*16 + (tid&15)];
    }

    if (!(own && s > 0)) {
      const unsigned long long* src =
          hb2 + ((size_t)(t & 1))*(B_*H_) + (size_t)b*H_ + tid*2;
      unsigned long long v0 = 0, v1 = 0;
      bool d0 = false, d1 = false;
      do {
        if (!d0) v0 = __hip_atomic_load(src,   __ATOMIC_RELAXED, __HIP_MEMORY_SCOPE_AGENT);
        if (!d1) v1 = __hip_atomic_load(src+1, __ATOMIC_RELAXED, __HIP_MEMORY_SCOPE_AGENT);
        d0 = d0 || ((unsigned)(v0 >> 32) == (unsigned)t);
        d1 = d1 || ((unsigned)(v1 >> 32) == (unsigned)t);
      } while (!(d0 && d1));
      union { unsigned u; float f; } a0u, a1u;
      a0u.u = (unsigned)v0; a1u.u = (unsigned)v1;
      hsh[p][2*tid]   = a0u.f;
      hsh[p][2*tid+1] = a1u.f;
    }
    __syncthreads();                               // the ONLY per-step barrier

    float xg0=0.f, xg1=0.f, xg2=0.f, xg3=0.f;
    if (q == 0) {
      xg0 = xpsh[p][c];      xg1 = xpsh[p][16+c];
      xg2 = xpsh[p][32+c];   xg3 = xpsh[p][48+c];
    }

    float a0=0.f, a1=0.f, a2=0.f, a3=0.f;
    #pragma unroll
    for (int k = 0; k < 8; ++k) {
      float4 h4 = *(const float4*)&hsh[p][q*4 + k*64];
      a0 = fmaf(w4[0][k].x,h4.x, fmaf(w4[0][k].y,h4.y, fmaf(w4[0][k].z,h4.z, fmaf(w4[0][k].w,h4.w, a0))));
      a1 = fmaf(w4[1][k].x,h4.x, fmaf(w4[1][k].y,h4.y, fmaf(w4[1][k].z,h4.z, fmaf(w4[1][k].w,h4.w, a1))));
      a2 = fmaf(w4[2][k].x,h4.x, fmaf(w4[2][k].y,h4.y, fmaf(w4[2][k].z,h4.z, fmaf(w4[2][k].w,h4.w, a2))));
      a3 = fmaf(w4[3][k].x,h4.x, fmaf(w4[3][k].y,h4.y, fmaf(w4[3][k].z,h4.z, fmaf(w4[3][k].w,h4.w, a3))));
    }
    #pragma unroll
    for (int msk = 1; msk < 16; msk <<= 1) {
      a0 += __shfl_xor(a0, msk, 64);
      a1 += __shfl_xor(a1, msk, 64);
      a2 += __shfl_xor(a2, msk, 64);
      a3 += __shfl_xor(a3, msk, 64);
    }

    if (q == 0) {
      float g0 = a0 + xg0, g1 = a1 + xg1, g2 = a2 + xg2, g3 = a3 + xg3;
      cc = sigm(g1)*cc + sigm(g0)*ftanh(g2);
      float hn = sigm(g3)*ftanh(cc);
      union { float f; unsigned u; } hu; hu.f = hn;
      unsigned long long wv =
          (((unsigned long long)(unsigned)(t + 1)) << 32) | (unsigned long long)hu.u;
      __hip_atomic_store(hb2 + ((size_t)((t+1) & 1))*(B_*H_) + (size_t)b*H_ + j, wv,
                         __ATOMIC_RELAXED, __HIP_MEMORY_SCOPE_AGENT);
      hsh[p^1][j] = hn;                  // self-bypass for next step
      enc_out[((size_t)b*L_ + t)*H_ + j] = hn;
      if (t == L_ - 1) hT[b*H_ + j] = hn;
    }
  }
  if (q == 0) cbuf[b*H_ + j] = cc;
}

// ---------------------------------------------------------------------------
// Fused launch: blocks [0,256) = recurrence chunk; blocks [256,256+ngemm) =
// concurrent GEMM (next chunk's Xproj, or ctx for finalized ENC rows).
// Recur is latency-bound (VALUBusy 21%) -> GEMM rides the idle SIMD slots.
// Recur blocks have the lowest IDs (dispatched resident first); GEMM blocks
// never wait on recur -> no deadlock possible, worst case lost overlap.
// ---------------------------------------------------------------------------
__global__ __launch_bounds__(256, 4) void fused_rg(
    const float* __restrict__ Xp, const float* __restrict__ Whh,
    float* __restrict__ enc_out, unsigned long long* __restrict__ hb2,
    float* __restrict__ cbuf, float* __restrict__ hT, int t0, int nsteps,
    const float* __restrict__ A, const float* __restrict__ W,
    const float* __restrict__ bias1, const float* __restrict__ bias2,
    float* __restrict__ C, int gN, int gK, int gCL, int gLtot, int gc0,
    int gCLc, int gLtotc, int gc0c, int gbx)
{
  if ((int)blockIdx.x < 256) {
    recur_body(Xp, Whh, enc_out, hb2, cbuf, hT, t0, nsteps);
  } else {
    const int b2 = (int)blockIdx.x - 256;
    gemm_body(A, W, bias1, bias2, C, gN, gK, gCL, gLtot, gc0,
              gCLc, gLtotc, gc0c, (b2 / gbx) * 128, (b2 % gbx) * 128);
  }
}

// ---------------------------------------------------------------------------
// out[b][n] = act( x1[b].W1[n,:K1] + (x2? x2[b].W2[n,:K2]) + bias1[n] (+bias2) )
// ---------------------------------------------------------------------------
__global__ __launch_bounds__(256) void dual_mv(
    const float* __restrict__ x1, const float* __restrict__ W1, int ld1, int K1,
    const float* __restrict__ x2, const float* __restrict__ W2, int ld2, int K2,
    const float* __restrict__ bias1, const float* __restrict__ bias2,
    float* __restrict__ out, int N, int act)
{
  const int w = blockIdx.x*4 + (threadIdx.x>>6);
  const int lane = threadIdx.x & 63;
  const int b = w / N, n = w % N;
  float s = 0.0f;
  for (int k = lane*4; k < K1; k += 256) {
    float4 xv = *(const float4*)(x1 + (size_t)b*K1 + k);
    float4 wv = *(const float4*)(W1 + (size_t)n*ld1 + k);
    s += xv.x*wv.x + xv.y*wv.y + xv.z*wv.z + xv.w*wv.w;
  }
  if (x2) {
    for (int k = lane*4; k < K2; k += 256) {
      float4 xv = *(const float4*)(x2 + (size_t)b*K2 + k);
      float4 wv = *(const float4*)(W2 + (size_t)n*ld2 + k);
      s += xv.x*wv.x + xv.y*wv.y + xv.z*wv.z + xv.w*wv.w;
    }
  }
  #pragma unroll
  for (int m=32; m>0; m>>=1) s += __shfl_xor(s, m, 64);
  if (lane == 0) {
    float r = s + bias1[n] + (bias2 ? bias2[n] : 0.0f);
    if (act) r = tanhf(r);
    out[(size_t)b*N + n] = r;
  }
}

__global__ void dec_cell(const float* __restrict__ g, float* __restrict__ c,
                         float* __restrict__ ht)
{
  int i = blockIdx.x*256 + threadIdx.x;     // 4096 threads
  int b = i >> 9, j = i & 511;
  const float* gb = g + (size_t)b*G4_;
  float gi_ = gb[j], gf = gb[H_+j], gg = gb[2*H_+j], go = gb[3*H_+j];
  float cc = c[i];
  cc = sigm(gf)*cc + sigm(gi_)*tanhf(gg);
  ht[i] = sigm(go)*tanhf(cc);
  c[i]  = cc;
}

__global__ __launch_bounds__(256) void dec_att(
    const float* __restrict__ inp, const float* __restrict__ ctx,
    const float* __restrict__ V, float* __restrict__ att)
{
  const int w = blockIdx.x*4 + (threadIdx.x>>6);  // w = b*L_ + l
  const int lane = threadIdx.x & 63;
  const int b = w >> 11;
  const float* cr = ctx + (size_t)w*H_;
  const float* ip = inp + (size_t)b*H_;
  float s = 0.0f;
  #pragma unroll
  for (int i=0;i<2;++i) {
    int k = lane*4 + i*256;
    float4 c4 = *(const float4*)(cr+k);
    float4 i4 = *(const float4*)(ip+k);
    float4 v4 = *(const float4*)(V+k);
    s += v4.x*tanhf(i4.x+c4.x) + v4.y*tanhf(i4.y+c4.y)
       + v4.z*tanhf(i4.z+c4.z) + v4.w*tanhf(i4.w+c4.w);
  }
  #pragma unroll
  for (int m=32; m>0; m>>=1) s += __shfl_xor(s, m, 64);
  if (lane == 0) att[w] = s;
}

__global__ __launch_bounds__(256) void dec_softmax(
    const float* __restrict__ att, const float* __restrict__ enc,
    int iter, int* __restrict__ chosen,
    float* __restrict__ out_alpha, float* __restrict__ out_ptr,
    float* __restrict__ x_next)
{
  const int b = blockIdx.x, tid = threadIdx.x;
  __shared__ float rv[256]; __shared__ int ri[256];
  __shared__ float s_mx, s_sum; __shared__ int s_idx;
  const int banned = iter ? chosen[b] : -1;
  float a[8]; float mx = -INFINITY;
  #pragma unroll
  for (int i=0;i<8;++i) {
    int l = (i<<8)+tid;
    float v = att[(size_t)b*L_ + l];
    if (l == banned) v = -INFINITY;
    a[i] = v; mx = fmaxf(mx, v);
  }
  rv[tid]=mx; __syncthreads();
  for (int s=128;s>0;s>>=1){ if (tid<s) rv[tid]=fmaxf(rv[tid],rv[tid+s]); __syncthreads(); }
  if (tid==0) s_mx = rv[0];
  __syncthreads();
  const float MX = s_mx;
  __syncthreads();
  float sum = 0.0f;
  #pragma unroll
  for (int i=0;i<8;++i) {
    int l = (i<<8)+tid;
    float pexp = (l == banned) ? 0.0f : expf(a[i]-MX);
    sum += pexp; a[i] = pexp;
  }
  rv[tid]=sum; __syncthreads();
  for (int s=128;s>0;s>>=1){ if (tid<s) rv[tid]+=rv[tid+s]; __syncthreads(); }
  if (tid==0) s_sum = rv[0];
  __syncthreads();
  const float inv = 1.0f/s_sum;
  __syncthreads();
  // argmax (first-occurrence on ties, matches jnp.argmax)
  float vb = -1.0f; int ib = 1<<30;
  #pragma unroll
  for (int i=0;i<8;++i) {
    int l = (i<<8)+tid;
    if (l != banned) { float v = a[i]; if (v > vb || (v == vb && l < ib)) { vb=v; ib=l; } }
  }
  rv[tid]=vb; ri[tid]=ib; __syncthreads();
  for (int s=128;s>0;s>>=1) {
    if (tid<s) {
      float v2=rv[tid+s]; int i2=ri[tid+s];
      if (v2 > rv[tid] || (v2 == rv[tid] && i2 < ri[tid])) { rv[tid]=v2; ri[tid]=i2; }
    }
    __syncthreads();
  }
  if (tid==0) {
    s_idx = ri[0];
    out_ptr[b*2+iter] = (float)ri[0];
    if (iter==0) chosen[b] = ri[0];
  }
  __syncthreads();
  #pragma unroll
  for (int i=0;i<8;++i) {
    int l = (i<<8)+tid;
    out_alpha[((size_t)b*2+iter)*L_ + l] = a[i]*inv;
  }
  const int idx = s_idx;
  for (int j=tid; j<H_; j+=256)
    x_next[(size_t)b*H_ + j] = enc[((size_t)b*L_ + idx)*H_ + j];
}

__global__ void dec_hidden1(const float* __restrict__ ctx, const float* __restrict__ alpha_all,
                            int iter, float* __restrict__ part)
{
  const int b = blockIdx.x >> 4, ch = blockIdx.x & 15;
  const int j = threadIdx.x;  // 512
  const float* al = alpha_all + ((size_t)b*2+iter)*L_ + ch*128;
  const float* cp = ctx + ((size_t)b*L_ + ch*128)*H_ + j;
  float s = 0.0f;
  for (int l=0; l<128; ++l) s += cp[(size_t)l*H_] * al[l];
  part[((size_t)b*16+ch)*H_ + j] = s;
}

__global__ void dec_hidden2(const float* __restrict__ part, float* __restrict__ hid)
{
  int i = blockIdx.x*256 + threadIdx.x;  // 4096
  int b = i >> 9, j = i & 511;
  float s = 0.0f;
  #pragma unroll
  for (int ch=0; ch<16; ++ch) s += part[((size_t)b*16+ch)*H_ + j];
  hid[i] = s;
}

// ---------------------------------------------------------------------------
extern "C" void kernel_launch(void* const* d_in, const int* in_sizes, int n_in,
                              void* d_out, int out_size, void* d_ws, size_t ws_size,
                              hipStream_t stream)
{
  const float* emb   = (const float*)d_in[0];
  const float* x0    = (const float*)d_in[1];
  const float* W_ih  = (const float*)d_in[2];
  const float* W_hh  = (const float*)d_in[3];
  const float* b_ih  = (const float*)d_in[4];
  const float* b_hh  = (const float*)d_in[5];
  const float* Wd_in = (const float*)d_in[6];
  const float* bd_in = (const float*)d_in[7];
  const float* Wd_hh = (const float*)d_in[8];
  const float* bd_hh = (const float*)d_in[9];
  const float* W_inp = (const float*)d_in[10];
  const float* b_inp = (const float*)d_in[11];
  const float* Wc    = (const float*)d_in[12];
  const float* bc    = (const float*)d_in[13];
  const float* V     = (const float*)d_in[14];
  const float* W_out = (const float*)d_in[15];
  const float* b_out = (const float*)d_in[16];

  const size_t BIG = 8388608;  // floats per XP/ENC buffer
  const size_t tail_floats = 8192*2 /*HB2*/ + 4096 + 4096 + 16384 + 4096*4 + 16384 + 65536 + 64;
  const bool dbuf = ws_size >= (3*BIG + tail_floats) * sizeof(float);

  float* ws  = (float*)d_ws;
  float* XPA = ws;                               // 8,388,608 floats; also CTX
  float* XPB = dbuf ? (XPA + BIG) : XPA;         // second Xproj buffer
  float* ENC = (dbuf ? XPB : XPA) + BIG;         // 8,388,608 floats
  unsigned long long* HB2 = (unsigned long long*)(ENC + BIG); // 8192 u64
  float* HB  = (float*)(HB2 + 8192);             // 4096 (h_T)
  float* CB  = HB + 4096;                        // 4096 (c state)
  float* DG  = CB + 4096;                        // 16384
  float* HT  = DG + 16384;                       // 4096
  float* INP = HT + 4096;                        // 4096
  float* ATT = INP + 4096;                       // 16384
  float* HID = ATT + 16384;                      // 4096
  float* XN  = HID + 4096;                       // 4096
  float* HD  = XN + 4096;                        // 4096
  float* PART = HD + 4096;                       // 65536
  int* CHOSEN = (int*)(PART + 65536);            // 8
  float* CTX = XPA;

  // zero tagged h buffer (tag0 = h0=0), h_T, c0 — contiguous region
  hipMemsetAsync(HB2, 0, 8192*sizeof(unsigned long long) + (4096+4096)*sizeof(float), stream);

  if (dbuf) {
    // 1. Xproj chunk0 -> XPA (exposed)
    gemm128<<<dim3(G4_/128, (B_*CL_)/128), 256, 0, stream>>>(
        emb, W_ih, b_ih, b_hh, XPA, G4_, E_, CL_, L_, 0*CL_, 1<<30, 0, 0);
    // 2-4. recur(chunk c) || Xproj(chunk c+1) into the other buffer
    float* xpsrc = XPA; float* xpdst = XPB;
    for (int c = 0; c < 3; ++c) {
      fused_rg<<<256 + 512, 256, 0, stream>>>(
          xpsrc, W_hh, ENC, HB2, CB, HB, c*CL_, CL_,
          emb, W_ih, b_ih, b_hh, xpdst, G4_, E_, CL_, L_, (c+1)*CL_,
          1<<30, 0, 0, /*gbx=*/16);
      float* tmp = xpsrc; xpsrc = xpdst; xpdst = tmp;
    }
    // 5. recur(chunk3) || ctx rows l<1536 (ENC chunks 0-2 finalized) -> CTX
    fused_rg<<<256 + 384, 256, 0, stream>>>(
        xpsrc, W_hh, ENC, HB2, CB, HB, 3*CL_, CL_,
        ENC, Wc, bc, nullptr, CTX, H_, H_, 1536, L_, 0,
        1536, L_, 0, /*gbx=*/4);
    // 6. ctx rows l in [1536,2048) (exposed, small)
    gemm128<<<dim3(H_/128, (B_*CL_)/128), 256, 0, stream>>>(
        ENC, Wc, bc, nullptr, CTX, H_, H_, CL_, L_, 1536, CL_, L_, 1536);
  } else {
    // serial fallback (= r5 schedule)
    for (int c = 0; c < 4; ++c) {
      gemm128<<<dim3(G4_/128, (B_*CL_)/128), 256, 0, stream>>>(
          emb, W_ih, b_ih, b_hh, XPA, G4_, E_, CL_, L_, c*CL_, 1<<30, 0, 0);
      fused_rg<<<256, 256, 0, stream>>>(
          XPA, W_hh, ENC, HB2, CB, HB, c*CL_, CL_,
          nullptr, nullptr, nullptr, nullptr, nullptr, 0, 0, 1, 1, 0, 1, 1, 0, 1);
    }
    gemm128<<<dim3(H_/128, (B_*L_)/128), 256, 0, stream>>>(
        ENC, Wc, bc, nullptr, CTX, H_, H_, L_, L_, 0, 1<<30, 0, 0);
  }

  // ---- decoder: 2 pointer steps ----
  float* out = (float*)d_out;
  const float* x_cur = x0;
  const float* h_cur = HB;
  for (int iter=0; iter<2; ++iter) {
    dual_mv<<<(B_*G4_)/4, 256, 0, stream>>>(x_cur, Wd_in, H_, H_,
                                            h_cur, Wd_hh, H_, H_,
                                            bd_in, bd_hh, DG, G4_, 0);
    dec_cell<<<16, 256, 0, stream>>>(DG, CB, HT);
    dual_mv<<<(B_*H_)/4, 256, 0, stream>>>(HT, W_inp, H_, H_,
                                           nullptr, nullptr, 0, 0,
                                           b_inp, nullptr, INP, H_, 0);
    dec_att<<<(B_*L_)/4, 256, 0, stream>>>(INP, CTX, V, ATT);
    dec_softmax<<<B_, 256, 0, stream>>>(ATT, ENC, iter, CHOSEN, out, out + 32768, XN);
    dec_hidden1<<<B_*16, 512, 0, stream>>>(CTX, out, iter, PART);
    dec_hidden2<<<16, 256, 0, stream>>>(PART, HID);
    dual_mv<<<(B_*H_)/4, 256, 0, stream>>>(HID, W_out, 2*H_, H_,
                                           HT, W_out + H_, 2*H_, H_,
                                           b_out, nullptr, HD, H_, 1);
    x_cur = XN; h_cur = HD;
  }
}

// Round 14
// 4868.143 us; speedup vs baseline: 2.6091x; 1.7241x over previous
//
#include <hip/hip_runtime.h>
#include <math.h>

#define B_   8
#define L_   2048
#define E_   768
#define H_   512
#define G4_  2048   // 4*H
#define CL_  512    // L chunk length

static __device__ __forceinline__ float sigm(float x){ return 1.0f/(1.0f+expf(-x)); }
static __device__ __forceinline__ float ftanh(float x){
  float ax = fabsf(x);
  float e  = expf(2.0f*ax);            // inf for large ax -> r = 1
  float r  = 1.0f - 2.0f/(e+1.0f);
  return copysignf(r, x);
}

// ---------------------------------------------------------------------------
// GEMM body: C[crow(r)][N] = A'[r,:K] . W[n,:K]^T + bias1 (+bias2)
// A row map: ab=r/CL, al=r%CL, arow=ab*Ltot+c0+al  (batch-chunk gather)
// C row map: cb=r/CLc, cl=r%CLc, crow=cb*Ltotc+c0c+cl (scatter for partial L)
// 128x128 tile, BK=16, 256 threads, 8x8 micro tile.
// ---------------------------------------------------------------------------
__device__ __forceinline__ void gemm_body(
    const float* __restrict__ A, const float* __restrict__ W,
    const float* __restrict__ bias1, const float* __restrict__ bias2,
    float* __restrict__ C, int N, int K, int CL, int Ltot, int c0,
    int CLc, int Ltotc, int c0c, int bm, int bn)
{
  __shared__ float As[16][132];
  __shared__ float Bs[16][132];
  const int tid = threadIdx.x;

  const int r  = tid >> 1;          // 0..127 (loader row)
  const int kq = (tid & 1) * 8;     // 0 or 8 (loader k-offset)
  const int am = bm + r;
  const int ab = am / CL, al = am % CL;
  const float* Arow = A + ((size_t)ab * Ltot + c0 + al) * K;
  const float* Wrow = W + (size_t)(bn + r) * K;

  const int tx = tid & 15, ty = tid >> 4;
  float acc[8][8] = {};

  for (int k0 = 0; k0 < K; k0 += 16) {
    float4 a0 = *(const float4*)(Arow + k0 + kq);
    float4 a1 = *(const float4*)(Arow + k0 + kq + 4);
    float4 w0 = *(const float4*)(Wrow + k0 + kq);
    float4 w1 = *(const float4*)(Wrow + k0 + kq + 4);
    __syncthreads();
    As[kq+0][r]=a0.x; As[kq+1][r]=a0.y; As[kq+2][r]=a0.z; As[kq+3][r]=a0.w;
    As[kq+4][r]=a1.x; As[kq+5][r]=a1.y; As[kq+6][r]=a1.z; As[kq+7][r]=a1.w;
    Bs[kq+0][r]=w0.x; Bs[kq+1][r]=w0.y; Bs[kq+2][r]=w0.z; Bs[kq+3][r]=w0.w;
    Bs[kq+4][r]=w1.x; Bs[kq+5][r]=w1.y; Bs[kq+6][r]=w1.z; Bs[kq+7][r]=w1.w;
    __syncthreads();
    #pragma unroll
    for (int k = 0; k < 16; ++k) {
      float4 x0 = *(const float4*)&As[k][ty*4];
      float4 x1 = *(const float4*)&As[k][64 + ty*4];
      float4 y0 = *(const float4*)&Bs[k][tx*4];
      float4 y1 = *(const float4*)&Bs[k][64 + tx*4];
      float av[8] = {x0.x,x0.y,x0.z,x0.w, x1.x,x1.y,x1.z,x1.w};
      float bv[8] = {y0.x,y0.y,y0.z,y0.w, y1.x,y1.y,y1.z,y1.w};
      #pragma unroll
      for (int i=0;i<8;++i)
        #pragma unroll
        for (int j=0;j<8;++j)
          acc[i][j] += av[i]*bv[j];
    }
  }

  float bs[8];
  #pragma unroll
  for (int j=0;j<4;++j) {
    int c0n = bn + tx*4 + j, c1n = bn + 64 + tx*4 + j;
    bs[j]   = bias1[c0n] + (bias2 ? bias2[c0n] : 0.0f);
    bs[4+j] = bias1[c1n] + (bias2 ? bias2[c1n] : 0.0f);
  }
  #pragma unroll
  for (int i=0;i<8;++i) {
    int r0 = bm + ((i<4) ? (ty*4+i) : (64 + ty*4 + (i-4)));
    int cb = r0 / CLc, cl = r0 % CLc;
    size_t crow = (size_t)cb * Ltotc + c0c + cl;
    float4 o0 = { acc[i][0]+bs[0], acc[i][1]+bs[1], acc[i][2]+bs[2], acc[i][3]+bs[3] };
    float4 o1 = { acc[i][4]+bs[4], acc[i][5]+bs[5], acc[i][6]+bs[6], acc[i][7]+bs[7] };
    *(float4*)&C[crow*N + bn + tx*4]      = o0;
    *(float4*)&C[crow*N + bn + 64 + tx*4] = o1;
  }
}

__global__ __launch_bounds__(256) void gemm128(
    const float* __restrict__ A, const float* __restrict__ W,
    const float* __restrict__ bias1, const float* __restrict__ bias2,
    float* __restrict__ C, int N, int K, int CL, int Ltot, int c0,
    int CLc, int Ltotc, int c0c)
{
  gemm_body(A, W, bias1, bias2, C, N, K, CL, Ltot, c0, CLc, Ltotc, c0c,
            blockIdx.y*128, blockIdx.x*128);
}

// ---------------------------------------------------------------------------
// Recurrence body = r5 champion VERBATIM (1245 us/dispatch, 2.43 us/step —
// best of 8 protocol variants r2..r11; MALL-RT-bound).
// ---------------------------------------------------------------------------
__device__ __forceinline__ void recur_body(
    const float* __restrict__ Xp, const float* __restrict__ Whh,
    float* __restrict__ enc_out, unsigned long long* __restrict__ hb2,
    float* __restrict__ cbuf, float* __restrict__ hT, int t0, int nsteps)
{
  const int tid = threadIdx.x;
  const int b   = blockIdx.x >> 5;     // batch 0..7
  const int m   = blockIdx.x & 31;     // h-slice 0..31
  const int c   = tid >> 4;            // cluster 0..15
  const int q   = tid & 15;            // lane within cluster
  const int j   = m*16 + c;            // owned h index

  __shared__ float hsh[2][512];
  __shared__ float xpsh[2][64];

  // weights: 4 gates x 1 row x 32 cols per thread (compiler streams via L2)
  float4 w4[4][8];
  #pragma unroll
  for (int gi = 0; gi < 4; ++gi) {
    const float* wr = Whh + ((size_t)(gi*H_ + j))*H_ + q*4;
    #pragma unroll
    for (int k = 0; k < 8; ++k) w4[gi][k] = *(const float4*)(wr + k*64);
  }
  float cc = 0.0f;
  if (q == 0) cc = cbuf[b*H_ + j];

  float xv = 0.0f;
  if (tid < 64)
    xv = Xp[((size_t)(b*CL_ + 0))*G4_ + (size_t)(tid>>4)*H_ + m*16 + (tid&15)];

  const bool own = ((tid >> 3) == m);  // this thread's 2 words are block-own

  for (int s = 0; s < nsteps; ++s) {
    const int t = t0 + s;
    const int p = s & 1;

    if (tid < 64) {
      xpsh[p][tid] = xv;
      if (s + 1 < nsteps)
        xv = Xp[((size_t)(b*CL_ + s + 1))*G4_ + (size_t)(tid>>4)*H_ + m*16 + (tid&15)];
    }

    if (!(own && s > 0)) {
      const unsigned long long* src =
          hb2 + ((size_t)(t & 1))*(B_*H_) + (size_t)b*H_ + tid*2;
      unsigned long long v0 = 0, v1 = 0;
      bool d0 = false, d1 = false;
      do {
        if (!d0) v0 = __hip_atomic_load(src,   __ATOMIC_RELAXED, __HIP_MEMORY_SCOPE_AGENT);
        if (!d1) v1 = __hip_atomic_load(src+1, __ATOMIC_RELAXED, __HIP_MEMORY_SCOPE_AGENT);
        d0 = d0 || ((unsigned)(v0 >> 32) == (unsigned)t);
        d1 = d1 || ((unsigned)(v1 >> 32) == (unsigned)t);
      } while (!(d0 && d1));
      union { unsigned u; float f; } a0u, a1u;
      a0u.u = (unsigned)v0; a1u.u = (unsigned)v1;
      hsh[p][2*tid]   = a0u.f;
      hsh[p][2*tid+1] = a1u.f;
    }
    __syncthreads();                               // the ONLY per-step barrier

    float xg0=0.f, xg1=0.f, xg2=0.f, xg3=0.f;
    if (q == 0) {
      xg0 = xpsh[p][c];      xg1 = xpsh[p][16+c];
      xg2 = xpsh[p][32+c];   xg3 = xpsh[p][48+c];
    }

    float a0=0.f, a1=0.f, a2=0.f, a3=0.f;
    #pragma unroll
    for (int k = 0; k < 8; ++k) {
      float4 h4 = *(const float4*)&hsh[p][q*4 + k*64];
      a0 = fmaf(w4[0][k].x,h4.x, fmaf(w4[0][k].y,h4.y, fmaf(w4[0][k].z,h4.z, fmaf(w4[0][k].w,h4.w, a0))));
      a1 = fmaf(w4[1][k].x,h4.x, fmaf(w4[1][k].y,h4.y, fmaf(w4[1][k].z,h4.z, fmaf(w4[1][k].w,h4.w, a1))));
      a2 = fmaf(w4[2][k].x,h4.x, fmaf(w4[2][k].y,h4.y, fmaf(w4[2][k].z,h4.z, fmaf(w4[2][k].w,h4.w, a2))));
      a3 = fmaf(w4[3][k].x,h4.x, fmaf(w4[3][k].y,h4.y, fmaf(w4[3][k].z,h4.z, fmaf(w4[3][k].w,h4.w, a3))));
    }
    #pragma unroll
    for (int msk = 1; msk < 16; msk <<= 1) {
      a0 += __shfl_xor(a0, msk, 64);
      a1 += __shfl_xor(a1, msk, 64);
      a2 += __shfl_xor(a2, msk, 64);
      a3 += __shfl_xor(a3, msk, 64);
    }

    if (q == 0) {
      float g0 = a0 + xg0, g1 = a1 + xg1, g2 = a2 + xg2, g3 = a3 + xg3;
      cc = sigm(g1)*cc + sigm(g0)*ftanh(g2);
      float hn = sigm(g3)*ftanh(cc);
      union { float f; unsigned u; } hu; hu.f = hn;
      unsigned long long wv =
          (((unsigned long long)(unsigned)(t + 1)) << 32) | (unsigned long long)hu.u;
      __hip_atomic_store(hb2 + ((size_t)((t+1) & 1))*(B_*H_) + (size_t)b*H_ + j, wv,
                         __ATOMIC_RELAXED, __HIP_MEMORY_SCOPE_AGENT);
      hsh[p^1][j] = hn;                  // self-bypass for next step
      enc_out[((size_t)b*L_ + t)*H_ + j] = hn;
      if (t == L_ - 1) hT[b*H_ + j] = hn;
    }
  }
  if (q == 0) cbuf[b*H_ + j] = cc;
}

// ---------------------------------------------------------------------------
// Fused launch: blocks [0,256) = recurrence chunk; blocks [256,256+ngemm) =
// concurrent GEMM (next chunk's Xproj, or ctx for finalized ENC rows).
// launch_bounds(256, 1): r13's (256,4) capped VGPR at 64 and spilled the
// recur path (WRITE_SIZE +44MB scratch) — THE bug. (256,1) restores r5's
// register budget; 3 blocks/CU still co-reside (38 KB LDS, ~12 waves/CU).
// Recur blocks have the lowest IDs (dispatched resident first); GEMM blocks
// never wait on recur -> no deadlock possible, worst case lost overlap.
// ---------------------------------------------------------------------------
__global__ __launch_bounds__(256, 1) void fused_rg(
    const float* __restrict__ Xp, const float* __restrict__ Whh,
    float* __restrict__ enc_out, unsigned long long* __restrict__ hb2,
    float* __restrict__ cbuf, float* __restrict__ hT, int t0, int nsteps,
    const float* __restrict__ A, const float* __restrict__ W,
    const float* __restrict__ bias1, const float* __restrict__ bias2,
    float* __restrict__ C, int gN, int gK, int gCL, int gLtot, int gc0,
    int gCLc, int gLtotc, int gc0c, int gbx)
{
  if ((int)blockIdx.x < 256) {
    recur_body(Xp, Whh, enc_out, hb2, cbuf, hT, t0, nsteps);
  } else {
    const int b2 = (int)blockIdx.x - 256;
    gemm_body(A, W, bias1, bias2, C, gN, gK, gCL, gLtot, gc0,
              gCLc, gLtotc, gc0c, (b2 / gbx) * 128, (b2 % gbx) * 128);
  }
}

// ---------------------------------------------------------------------------
// out[b][n] = act( x1[b].W1[n,:K1] + (x2? x2[b].W2[n,:K2]) + bias1[n] (+bias2) )
// ---------------------------------------------------------------------------
__global__ __launch_bounds__(256) void dual_mv(
    const float* __restrict__ x1, const float* __restrict__ W1, int ld1, int K1,
    const float* __restrict__ x2, const float* __restrict__ W2, int ld2, int K2,
    const float* __restrict__ bias1, const float* __restrict__ bias2,
    float* __restrict__ out, int N, int act)
{
  const int w = blockIdx.x*4 + (threadIdx.x>>6);
  const int lane = threadIdx.x & 63;
  const int b = w / N, n = w % N;
  float s = 0.0f;
  for (int k = lane*4; k < K1; k += 256) {
    float4 xv = *(const float4*)(x1 + (size_t)b*K1 + k);
    float4 wv = *(const float4*)(W1 + (size_t)n*ld1 + k);
    s += xv.x*wv.x + xv.y*wv.y + xv.z*wv.z + xv.w*wv.w;
  }
  if (x2) {
    for (int k = lane*4; k < K2; k += 256) {
      float4 xv = *(const float4*)(x2 + (size_t)b*K2 + k);
      float4 wv = *(const float4*)(W2 + (size_t)n*ld2 + k);
      s += xv.x*wv.x + xv.y*wv.y + xv.z*wv.z + xv.w*wv.w;
    }
  }
  #pragma unroll
  for (int m=32; m>0; m>>=1) s += __shfl_xor(s, m, 64);
  if (lane == 0) {
    float r = s + bias1[n] + (bias2 ? bias2[n] : 0.0f);
    if (act) r = tanhf(r);
    out[(size_t)b*N + n] = r;
  }
}

__global__ void dec_cell(const float* __restrict__ g, float* __restrict__ c,
                         float* __restrict__ ht)
{
  int i = blockIdx.x*256 + threadIdx.x;     // 4096 threads
  int b = i >> 9, j = i & 511;
  const float* gb = g + (size_t)b*G4_;
  float gi_ = gb[j], gf = gb[H_+j], gg = gb[2*H_+j], go = gb[3*H_+j];
  float cc = c[i];
  cc = sigm(gf)*cc + sigm(gi_)*tanhf(gg);
  ht[i] = sigm(go)*tanhf(cc);
  c[i]  = cc;
}

__global__ __launch_bounds__(256) void dec_att(
    const float* __restrict__ inp, const float* __restrict__ ctx,
    const float* __restrict__ V, float* __restrict__ att)
{
  const int w = blockIdx.x*4 + (threadIdx.x>>6);  // w = b*L_ + l
  const int lane = threadIdx.x & 63;
  const int b = w >> 11;
  const float* cr = ctx + (size_t)w*H_;
  const float* ip = inp + (size_t)b*H_;
  float s = 0.0f;
  #pragma unroll
  for (int i=0;i<2;++i) {
    int k = lane*4 + i*256;
    float4 c4 = *(const float4*)(cr+k);
    float4 i4 = *(const float4*)(ip+k);
    float4 v4 = *(const float4*)(V+k);
    s += v4.x*tanhf(i4.x+c4.x) + v4.y*tanhf(i4.y+c4.y)
       + v4.z*tanhf(i4.z+c4.z) + v4.w*tanhf(i4.w+c4.w);
  }
  #pragma unroll
  for (int m=32; m>0; m>>=1) s += __shfl_xor(s, m, 64);
  if (lane == 0) att[w] = s;
}

__global__ __launch_bounds__(256) void dec_softmax(
    const float* __restrict__ att, const float* __restrict__ enc,
    int iter, int* __restrict__ chosen,
    float* __restrict__ out_alpha, float* __restrict__ out_ptr,
    float* __restrict__ x_next)
{
  const int b = blockIdx.x, tid = threadIdx.x;
  __shared__ float rv[256]; __shared__ int ri[256];
  __shared__ float s_mx, s_sum; __shared__ int s_idx;
  const int banned = iter ? chosen[b] : -1;
  float a[8]; float mx = -INFINITY;
  #pragma unroll
  for (int i=0;i<8;++i) {
    int l = (i<<8)+tid;
    float v = att[(size_t)b*L_ + l];
    if (l == banned) v = -INFINITY;
    a[i] = v; mx = fmaxf(mx, v);
  }
  rv[tid]=mx; __syncthreads();
  for (int s=128;s>0;s>>=1){ if (tid<s) rv[tid]=fmaxf(rv[tid],rv[tid+s]); __syncthreads(); }
  if (tid==0) s_mx = rv[0];
  __syncthreads();
  const float MX = s_mx;
  __syncthreads();
  float sum = 0.0f;
  #pragma unroll
  for (int i=0;i<8;++i) {
    int l = (i<<8)+tid;
    float pexp = (l == banned) ? 0.0f : expf(a[i]-MX);
    sum += pexp; a[i] = pexp;
  }
  rv[tid]=sum; __syncthreads();
  for (int s=128;s>0;s>>=1){ if (tid<s) rv[tid]+=rv[tid+s]; __syncthreads(); }
  if (tid==0) s_sum = rv[0];
  __syncthreads();
  const float inv = 1.0f/s_sum;
  __syncthreads();
  // argmax (first-occurrence on ties, matches jnp.argmax)
  float vb = -1.0f; int ib = 1<<30;
  #pragma unroll
  for (int i=0;i<8;++i) {
    int l = (i<<8)+tid;
    if (l != banned) { float v = a[i]; if (v > vb || (v == vb && l < ib)) { vb=v; ib=l; } }
  }
  rv[tid]=vb; ri[tid]=ib; __syncthreads();
  for (int s=128;s>0;s>>=1) {
    if (tid<s) {
      float v2=rv[tid+s]; int i2=ri[tid+s];
      if (v2 > rv[tid] || (v2 == rv[tid] && i2 < ri[tid])) { rv[tid]=v2; ri[tid]=i2; }
    }
    __syncthreads();
  }
  if (tid==0) {
    s_idx = ri[0];
    out_ptr[b*2+iter] = (float)ri[0];
    if (iter==0) chosen[b] = ri[0];
  }
  __syncthreads();
  #pragma unroll
  for (int i=0;i<8;++i) {
    int l = (i<<8)+tid;
    out_alpha[((size_t)b*2+iter)*L_ + l] = a[i]*inv;
  }
  const int idx = s_idx;
  for (int j=tid; j<H_; j+=256)
    x_next[(size_t)b*H_ + j] = enc[((size_t)b*L_ + idx)*H_ + j];
}

__global__ void dec_hidden1(const float* __restrict__ ctx, const float* __restrict__ alpha_all,
                            int iter, float* __restrict__ part)
{
  const int b = blockIdx.x >> 4, ch = blockIdx.x & 15;
  const int j = threadIdx.x;  // 512
  const float* al = alpha_all + ((size_t)b*2+iter)*L_ + ch*128;
  const float* cp = ctx + ((size_t)b*L_ + ch*128)*H_ + j;
  float s = 0.0f;
  for (int l=0; l<128; ++l) s += cp[(size_t)l*H_] * al[l];
  part[((size_t)b*16+ch)*H_ + j] = s;
}

__global__ void dec_hidden2(const float* __restrict__ part, float* __restrict__ hid)
{
  int i = blockIdx.x*256 + threadIdx.x;  // 4096
  int b = i >> 9, j = i & 511;
  float s = 0.0f;
  #pragma unroll
  for (int ch=0; ch<16; ++ch) s += part[((size_t)b*16+ch)*H_ + j];
  hid[i] = s;
}

// ---------------------------------------------------------------------------
extern "C" void kernel_launch(void* const* d_in, const int* in_sizes, int n_in,
                              void* d_out, int out_size, void* d_ws, size_t ws_size,
                              hipStream_t stream)
{
  const float* emb   = (const float*)d_in[0];
  const float* x0    = (const float*)d_in[1];
  const float* W_ih  = (const float*)d_in[2];
  const float* W_hh  = (const float*)d_in[3];
  const float* b_ih  = (const float*)d_in[4];
  const float* b_hh  = (const float*)d_in[5];
  const float* Wd_in = (const float*)d_in[6];
  const float* bd_in = (const float*)d_in[7];
  const float* Wd_hh = (const float*)d_in[8];
  const float* bd_hh = (const float*)d_in[9];
  const float* W_inp = (const float*)d_in[10];
  const float* b_inp = (const float*)d_in[11];
  const float* Wc    = (const float*)d_in[12];
  const float* bc    = (const float*)d_in[13];
  const float* V     = (const float*)d_in[14];
  const float* W_out = (const float*)d_in[15];
  const float* b_out = (const float*)d_in[16];

  const size_t BIG = 8388608;  // floats per XP/ENC buffer
  const size_t tail_floats = 8192*2 /*HB2*/ + 4096 + 4096 + 16384 + 4096*4 + 16384 + 65536 + 64;
  const bool dbuf = ws_size >= (3*BIG + tail_floats) * sizeof(float);

  float* ws  = (float*)d_ws;
  float* XPA = ws;                               // 8,388,608 floats; also CTX
  float* XPB = dbuf ? (XPA + BIG) : XPA;         // second Xproj buffer
  float* ENC = (dbuf ? XPB : XPA) + BIG;         // 8,388,608 floats
  unsigned long long* HB2 = (unsigned long long*)(ENC + BIG); // 8192 u64
  float* HB  = (float*)(HB2 + 8192);             // 4096 (h_T)
  float* CB  = HB + 4096;                        // 4096 (c state)
  float* DG  = CB + 4096;                        // 16384
  float* HT  = DG + 16384;                       // 4096
  float* INP = HT + 4096;                        // 4096
  float* ATT = INP + 4096;                       // 16384
  float* HID = ATT + 16384;                      // 4096
  float* XN  = HID + 4096;                       // 4096
  float* HD  = XN + 4096;                        // 4096
  float* PART = HD + 4096;                       // 65536
  int* CHOSEN = (int*)(PART + 65536);            // 8
  float* CTX = XPA;

  // zero tagged h buffer (tag0 = h0=0), h_T, c0 — contiguous region
  hipMemsetAsync(HB2, 0, 8192*sizeof(unsigned long long) + (4096+4096)*sizeof(float), stream);

  if (dbuf) {
    // 1. Xproj chunk0 -> XPA (exposed)
    gemm128<<<dim3(G4_/128, (B_*CL_)/128), 256, 0, stream>>>(
        emb, W_ih, b_ih, b_hh, XPA, G4_, E_, CL_, L_, 0*CL_, 1<<30, 0, 0);
    // 2-4. recur(chunk c) || Xproj(chunk c+1) into the other buffer
    float* xpsrc = XPA; float* xpdst = XPB;
    for (int c = 0; c < 3; ++c) {
      fused_rg<<<256 + 512, 256, 0, stream>>>(
          xpsrc, W_hh, ENC, HB2, CB, HB, c*CL_, CL_,
          emb, W_ih, b_ih, b_hh, xpdst, G4_, E_, CL_, L_, (c+1)*CL_,
          1<<30, 0, 0, /*gbx=*/16);
      float* tmp = xpsrc; xpsrc = xpdst; xpdst = tmp;
    }
    // 5. recur(chunk3) || ctx rows l<1536 (ENC chunks 0-2 finalized) -> CTX
    fused_rg<<<256 + 384, 256, 0, stream>>>(
        xpsrc, W_hh, ENC, HB2, CB, HB, 3*CL_, CL_,
        ENC, Wc, bc, nullptr, CTX, H_, H_, 1536, L_, 0,
        1536, L_, 0, /*gbx=*/4);
    // 6. ctx rows l in [1536,2048) (exposed, small)
    gemm128<<<dim3(H_/128, (B_*CL_)/128), 256, 0, stream>>>(
        ENC, Wc, bc, nullptr, CTX, H_, H_, CL_, L_, 1536, CL_, L_, 1536);
  } else {
    // serial fallback (= r5 schedule)
    for (int c = 0; c < 4; ++c) {
      gemm128<<<dim3(G4_/128, (B_*CL_)/128), 256, 0, stream>>>(
          emb, W_ih, b_ih, b_hh, XPA, G4_, E_, CL_, L_, c*CL_, 1<<30, 0, 0);
      fused_rg<<<256, 256, 0, stream>>>(
          XPA, W_hh, ENC, HB2, CB, HB, c*CL_, CL_,
          nullptr, nullptr, nullptr, nullptr, nullptr, 0, 0, 1, 1, 0, 1, 1, 0, 1);
    }
    gemm128<<<dim3(H_/128, (B_*L_)/128), 256, 0, stream>>>(
        ENC, Wc, bc, nullptr, CTX, H_, H_, L_, L_, 0, 1<<30, 0, 0);
  }

  // ---- decoder: 2 pointer steps ----
  float* out = (float*)d_out;
  const float* x_cur = x0;
  const float* h_cur = HB;
  for (int iter=0; iter<2; ++iter) {
    dual_mv<<<(B_*G4_)/4, 256, 0, stream>>>(x_cur, Wd_in, H_, H_,
                                            h_cur, Wd_hh, H_, H_,
                                            bd_in, bd_hh, DG, G4_, 0);
    dec_cell<<<16, 256, 0, stream>>>(DG, CB, HT);
    dual_mv<<<(B_*H_)/4, 256, 0, stream>>>(HT, W_inp, H_, H_,
                                           nullptr, nullptr, 0, 0,
                                           b_inp, nullptr, INP, H_, 0);
    dec_att<<<(B_*L_)/4, 256, 0, stream>>>(INP, CTX, V, ATT);
    dec_softmax<<<B_, 256, 0, stream>>>(ATT, ENC, iter, CHOSEN, out, out + 32768, XN);
    dec_hidden1<<<B_*16, 512, 0, stream>>>(CTX, out, iter, PART);
    dec_hidden2<<<16, 256, 0, stream>>>(PART, HID);
    dual_mv<<<(B_*H_)/4, 256, 0, stream>>>(HID, W_out, 2*H_, H_,
                                           HT, W_out + H_, 2*H_, H_,
                                           b_out, nullptr, HD, H_, 1);
    x_cur = XN; h_cur = HD;
  }
}